// Round 9
// baseline (3209.044 us; speedup 1.0000x reference)
//
#include <hip/hip_runtime.h>
#include <math.h>

#define NN_ 200000
#define EE_ 400000
#define HH  96
#define LL  6
#define BB  4096
#define NT_ 12500     // node tiles of 16
#define PLE (NN_ * 16)   // plane stride in ushorts (16 elems/node/plane)
#define SCAN_B 1024
#define NB_SCAN 196   // cdiv(200000, 1024)

typedef short s8v __attribute__((ext_vector_type(8)));
typedef float f4v __attribute__((ext_vector_type(4)));
typedef float f2v __attribute__((ext_vector_type(2)));

static inline int cdiv(int a, int b) { return (a + b - 1) / b; }

__device__ __forceinline__ float sigmoidf_(float x) { return 1.0f / (1.0f + __expf(-x)); }
__device__ __forceinline__ float tanhf_(float x) { return 1.0f - 2.0f / (__expf(2.0f * x) + 1.0f); }
__device__ __forceinline__ unsigned short f2bf(float x) {
    unsigned u = __float_as_uint(x);
    unsigned r = u + 0x7FFF + ((u >> 16) & 1);   // RNE
    return (unsigned short)(r >> 16);
}
__device__ __forceinline__ float bf2f(unsigned short u) {
    return __uint_as_float(((unsigned)u) << 16);
}
// load 8 consecutive fp32 and convert to a bf16x8 MFMA fragment (in-register)
__device__ __forceinline__ s8v load_bf8(const float* __restrict__ p) {
    float4 v0 = *(const float4*)p;
    float4 v1 = *(const float4*)(p + 4);
    s8v r;
    r[0] = (short)f2bf(v0.x); r[1] = (short)f2bf(v0.y);
    r[2] = (short)f2bf(v0.z); r[3] = (short)f2bf(v0.w);
    r[4] = (short)f2bf(v1.x); r[5] = (short)f2bf(v1.y);
    r[6] = (short)f2bf(v1.z); r[7] = (short)f2bf(v1.w);
    return r;
}

// bf16-pair accumulate: u holds 2 bf16; low elem -> a[0], high elem -> a[1]
__device__ __forceinline__ void accu_(f2v& a, unsigned u) {
    a[0] += __uint_as_float(u << 16);
    a[1] += __uint_as_float(u & 0xFFFF0000u);
}
__device__ __forceinline__ void acc_row_(f2v* ag2, const uint4& u, int ks) {
    accu_(ag2[ks * 4 + 0], u.x); accu_(ag2[ks * 4 + 1], u.y);
    accu_(ag2[ks * 4 + 2], u.z); accu_(ag2[ks * 4 + 3], u.w);
}

// ---------------------------------------------------------------------------
// MLP weight pack (B-operand fragment order, read from global):
// Bp[((k>>5)*N + n)*32 + ((k>>3)&3)*8 + (k&7)] = bf16(B[k*N + n])
// ---------------------------------------------------------------------------
__global__ void packB_k(const float* __restrict__ B, unsigned short* __restrict__ Bp,
                        int K, int N)
{
    int idx = blockIdx.x * 256 + threadIdx.x;
    if (idx >= K * N) return;
    int k = idx / N, n = idx % N;
    Bp[(((size_t)(k >> 5) * N + n) * 4 + ((k >> 3) & 3)) * 8 + (k & 7)] = f2bf(B[idx]);
}

// ---------------------------------------------------------------------------
// Wp pack, weight-stationary A-operand order:
// offset = (((l*6 + jb)*3 + ks)*64 + lane)*8 + j
//   holds  W[l][k = ks*32 + (lane>>4)*8 + j][n = jb*16 + (lane&15)]
// ---------------------------------------------------------------------------
__global__ void packWp_k(const float* __restrict__ W, unsigned short* __restrict__ Wp)
{
    int idx = blockIdx.x * 256 + threadIdx.x;
    if (idx >= LL * 6 * 3 * 64 * 8) return;
    int j    = idx & 7;
    int lane = (idx >> 3) & 63;
    int rest = idx >> 9;
    int ks = rest % 3;
    int jb = (rest / 3) % 6;
    int l  = rest / 18;
    int quad = lane >> 4, lc = lane & 15;
    int k = ks * 32 + quad * 8 + j;
    int n = jb * 16 + lc;
    Wp[idx] = f2bf(W[(size_t)l * 9216 + (size_t)k * 96 + n]);
}

// ---------------------------------------------------------------------------
// Wgc pack: COMPACT gate weights [6 jb][18 ksb][64 lane][8 j]  (zeros removed)
//   ksb 0..5   -> g=0 (r), ks=ksb      (full K: agg then h)
//   ksb 6..11  -> g=1 (z), ks=ksb-6
//   ksb 12..14 -> g=2 (i_n), ks=ksb-12 (k<96: agg side only)
//   ksb 15..17 -> g=3 (h_n), ks=ksb-12 -> 3..5 (k>=96: h side only)
// value at k = ks*32 + quad*8 + j, n = g*96 + jb*16 + lc
// ---------------------------------------------------------------------------
__global__ void packWgc_k(const float* __restrict__ wih, const float* __restrict__ whh,
                          unsigned short* __restrict__ Wgc)
{
    int idx = blockIdx.x * 256 + threadIdx.x;
    if (idx >= 6 * 18 * 64 * 8) return;
    int j    = idx & 7;
    int lane = (idx >> 3) & 63;
    int rest = idx >> 9;          // < 108
    int ksb = rest % 18;
    int jb  = rest / 18;
    int quad = lane >> 4, lc = lane & 15;
    int g, ks;
    if (ksb < 6)       { g = 0; ks = ksb; }
    else if (ksb < 12) { g = 1; ks = ksb - 6; }
    else if (ksb < 15) { g = 2; ks = ksb - 12; }
    else               { g = 3; ks = ksb - 12; }   // 3..5
    int k = ks * 32 + quad * 8 + j;
    int n = g * 96 + jb * 16 + lc;
    float v;
    if (n < 192) {
        v = (k < 96) ? wih[(size_t)n * 96 + k] : whh[(size_t)n * 96 + (k - 96)];
    } else if (n < 288) {
        int jj = n - 192;
        v = wih[(size_t)(192 + jj) * 96 + k];          // g=2: k<96 guaranteed
    } else {
        int jj = n - 288;
        v = whh[(size_t)(192 + jj) * 96 + (k - 96)];   // g=3: k>=96 guaranteed
    }
    Wgc[idx] = f2bf(v);
}

// combined bias pack: bs[0..95]=bih_r+bhh_r, [96..191]=bih_z+bhh_z,
// [192..287]=bih_n, [288..383]=bhh_n
__global__ void bpack_k(const float* __restrict__ bih, const float* __restrict__ bhh,
                        float* __restrict__ bs)
{
    int j = threadIdx.x;
    if (j >= 96) return;
    bs[j]        = bih[j] + bhh[j];
    bs[96 + j]   = bih[96 + j] + bhh[96 + j];
    bs[192 + j]  = bih[192 + j];
    bs[288 + j]  = bhh[192 + j];
}

// pad into PLANE layout: hbf[p*PLE + n*16 + jj] = elem j=p*16+jj of node n.
// idx runs linearly over the plane layout -> fully coalesced 2B stores.
__global__ void pad_k(const float* __restrict__ x, unsigned short* __restrict__ hbf)
{
    int idx = blockIdx.x * 256 + threadIdx.x;
    if (idx >= 6 * PLE) return;
    int p  = idx / PLE;
    int r  = idx - p * PLE;
    int n  = r >> 4;
    int jj = r & 15;
    int j  = p * 16 + jj;
    float v = (j < 32) ? x[n * 32 + j] : 0.f;
    hbf[idx] = f2bf(v);
}

// --------------------------- CSR build (once per component) -----------------
__global__ void deg_k(const int* __restrict__ ei, int* __restrict__ deg)
{
    int e = blockIdx.x * 256 + threadIdx.x;
    if (e >= EE_) return;
    atomicAdd(&deg[ei[EE_ + e]], 1);
}

__global__ __launch_bounds__(SCAN_B) void scan1_k(
    const int* __restrict__ deg, int* __restrict__ rp, int* __restrict__ bsum)
{
    __shared__ int sh[SCAN_B];
    int i = blockIdx.x * SCAN_B + threadIdx.x;
    int v = (i < NN_) ? deg[i] : 0;
    sh[threadIdx.x] = v;
    __syncthreads();
    for (int off = 1; off < SCAN_B; off <<= 1) {
        int t = (threadIdx.x >= off) ? sh[threadIdx.x - off] : 0;
        __syncthreads();
        sh[threadIdx.x] += t;
        __syncthreads();
    }
    if (i < NN_) rp[i] = sh[threadIdx.x] - v;     // exclusive within block
    if (threadIdx.x == SCAN_B - 1) bsum[blockIdx.x] = sh[threadIdx.x];
}

__global__ __launch_bounds__(256) void scan2_k(int* __restrict__ bsum)
{
    __shared__ int sh[256];
    int v = (threadIdx.x < NB_SCAN) ? bsum[threadIdx.x] : 0;
    sh[threadIdx.x] = v;
    __syncthreads();
    for (int off = 1; off < 256; off <<= 1) {
        int t = (threadIdx.x >= off) ? sh[threadIdx.x - off] : 0;
        __syncthreads();
        sh[threadIdx.x] += t;
        __syncthreads();
    }
    if (threadIdx.x < NB_SCAN) bsum[threadIdx.x] = sh[threadIdx.x] - v;  // exclusive
}

__global__ void scan3_k(int* __restrict__ rp, const int* __restrict__ bsum,
                        int* __restrict__ cur)
{
    int i = blockIdx.x * 256 + threadIdx.x;
    if (i < NN_) {
        int r = rp[i] + bsum[i / SCAN_B];
        rp[i] = r;
        cur[i] = r;
    }
    if (i == 0) rp[NN_] = EE_;
}

// srcs stores BYTE offsets within a plane (s * 32).
__global__ void fill_k(const int* __restrict__ ei, int* __restrict__ cur,
                       int* __restrict__ srcs)
{
    int e = blockIdx.x * 256 + threadIdx.x;
    if (e >= EE_) return;
    int s = ei[e];
    int d = ei[EE_ + e];
    int pos = atomicAdd(&cur[d], 1);
    srcs[pos] = s * 32;
}

// batch row pointers: batch[] is sorted, detect segment boundaries.
__global__ void brp_k(const int* __restrict__ bat, int* __restrict__ rpb)
{
    int i = blockIdx.x * 256 + threadIdx.x;
    if (i >= NN_) return;
    int b = bat[i];
    if (i == 0) {
        for (int q = 0; q <= b; q++) rpb[q] = 0;
    } else {
        int p = bat[i - 1];
        for (int q = p + 1; q <= b; q++) rpb[q] = i;
    }
    if (i == NN_ - 1) {
        for (int q = b + 1; q <= BB; q++) rpb[q] = NN_;
    }
}

// ---------------------------------------------------------------------------
// Phase A: aggbf = sum over in-edges of hbf[src]  (plane layout in AND out).
// Lane (quad,lc): node lc, feature slice ks*32+quad*8 -> plane 2ks+(quad>>1),
// intra-plane byte offset node*32 + (quad&1)*16.
// Stores: 2x512B contiguous per instruction (full lines, no amplification).
// ---------------------------------------------------------------------------
__global__ __launch_bounds__(128) void agg_k(
    const int* __restrict__ rp, const int* __restrict__ srcs,
    const unsigned short* __restrict__ hbf,
    unsigned short* __restrict__ aggbf)
{
    int tid  = threadIdx.x;
    int wave = tid >> 6;
    int lane = tid & 63;
    int quad = lane >> 4;
    int lc   = lane & 15;
    int nT0  = blockIdx.x * 4 + wave * 2;
    int q2 = quad >> 1, q1 = quad & 1;

    const char* g0 = (const char*)(hbf + (size_t)(0 + q2) * PLE) + q1 * 16;
    const char* g1 = (const char*)(hbf + (size_t)(2 + q2) * PLE) + q1 * 16;
    const char* g2 = (const char*)(hbf + (size_t)(4 + q2) * PLE) + q1 * 16;

    #pragma unroll
    for (int t = 0; t < 2; t++) {
        int node = (nT0 + t) * 16 + lc;
        f2v ag2[12];
        #pragma unroll
        for (int i = 0; i < 12; i++) ag2[i] = (f2v){0.f, 0.f};
        int e = rp[node], e1 = rp[node + 1];
        for (; e < e1; e++) {
            int off = srcs[e];
            uint4 u0 = *(const uint4*)(g0 + off);
            uint4 u1 = *(const uint4*)(g1 + off);
            uint4 u2 = *(const uint4*)(g2 + off);
            acc_row_(ag2, u0, 0); acc_row_(ag2, u1, 1); acc_row_(ag2, u2, 2);
        }
        #pragma unroll
        for (int ks = 0; ks < 3; ks++) {
            unsigned p0 = (unsigned)f2bf(ag2[ks * 4 + 0][0]) | ((unsigned)f2bf(ag2[ks * 4 + 0][1]) << 16);
            unsigned p1 = (unsigned)f2bf(ag2[ks * 4 + 1][0]) | ((unsigned)f2bf(ag2[ks * 4 + 1][1]) << 16);
            unsigned p2 = (unsigned)f2bf(ag2[ks * 4 + 2][0]) | ((unsigned)f2bf(ag2[ks * 4 + 2][1]) << 16);
            unsigned p3 = (unsigned)f2bf(ag2[ks * 4 + 3][0]) | ((unsigned)f2bf(ag2[ks * 4 + 3][1]) << 16);
            *(uint4*)(aggbf + (size_t)(2 * ks + q2) * PLE + (size_t)node * 16 + q1 * 8) =
                make_uint4(p0, p1, p2, p3);
        }
    }
}

// ---------------------------------------------------------------------------
// Phase B v7: GRU update, bf16 plane-layout state, jb-half split.
// 512 thr (8 waves); grid (cdiv(NT_,16), 2); half = blockIdx.y (jb 3h..3h+2).
// Halves write DISJOINT planes -> every store instruction covers 512B
// contiguous (full lines). LDS 73,728 B -> 2 blocks/CU.
// ---------------------------------------------------------------------------
__global__ __launch_bounds__(512) void gru_k(
    const unsigned short* __restrict__ aggbf,
    const unsigned short* __restrict__ Wp,    // this layer: [6][3][64][8] (global)
    const unsigned short* __restrict__ Wgc,   // compact [6][18][64][8]
    const float* __restrict__ bs,
    const unsigned short* __restrict__ hbf_prev,
    unsigned short* __restrict__ hbf_next,
    float* __restrict__ h,
    int writeH)
{
    __shared__ unsigned short lw[27648];          // 55,296 B: this half's 3 jb
    __shared__ unsigned short as_[8][32][36];     // 18,432 B transpose buffer
    int tid  = threadIdx.x;
    int half = blockIdx.y;

    // ---- stage this half's Wgc -> LDS (coalesced 16B) ----
    {
        const uint4* src = (const uint4*)Wgc + (size_t)half * 3456;
        uint4* dst = (uint4*)lw;
        #pragma unroll
        for (int it = 0; it < 7; it++) {
            int i = it * 512 + tid;
            if (i < 3456) dst[i] = src[i];
        }
    }
    __syncthreads();

    int wave = tid >> 6;
    int lane = tid & 63;
    int quad = lane >> 4;
    int lc   = lane & 15;
    int nT0  = blockIdx.x * 16 + wave * 2;
    int q2 = quad >> 1, q1 = quad & 1;

    bool val[2];
    val[0] = (nT0 + 0) < NT_;
    val[1] = (nT0 + 1) < NT_;

    s8v z8;
    #pragma unroll
    for (int q = 0; q < 8; q++) z8[q] = 0;

    // coalesced fragment loads (plane layout): messages + own-row h
    s8v hg[2][3], dh[2][3];
    #pragma unroll
    for (int t = 0; t < 2; t++) {
        int node = (nT0 + t) * 16 + lc;
        #pragma unroll
        for (int ks = 0; ks < 3; ks++) {
            size_t base = (size_t)(2 * ks + q2) * PLE + (size_t)node * 16 + q1 * 8;
            if (val[t]) {
                hg[t][ks] = *(const s8v*)(aggbf    + base);
                dh[t][ks] = *(const s8v*)(hbf_prev + base);
            } else {
                hg[t][ks] = z8;
                dh[t][ks] = z8;
            }
        }
    }

    // ---- Stage 1: agg@W (ALL 96 cols) fused with wave-local as_ transpose ----
    s8v d[2][6];
    #pragma unroll
    for (int kb = 0; kb < 3; kb++) {
        #pragma unroll
        for (int jj = 0; jj < 2; jj++) {
            int jb = kb * 2 + jj;
            f4v a1[2] = {};
            #pragma unroll
            for (int ks = 0; ks < 3; ks++) {
                s8v w = *(const s8v*)(Wp + ((size_t)(jb * 3 + ks) * 64 + lane) * 8);
                a1[0] = __builtin_amdgcn_mfma_f32_16x16x32_bf16(w, hg[0][ks], a1[0], 0, 0, 0);
                a1[1] = __builtin_amdgcn_mfma_f32_16x16x32_bf16(w, hg[1][ks], a1[1], 0, 0, 0);
            }
            #pragma unroll
            for (int t = 0; t < 2; t++) {
                unsigned short o0 = f2bf(a1[t][0]), o1 = f2bf(a1[t][1]);
                unsigned short o2 = f2bf(a1[t][2]), o3 = f2bf(a1[t][3]);
                *(uint2*)&as_[wave][t * 16 + lc][jj * 16 + quad * 4] =
                    make_uint2((unsigned)o0 | ((unsigned)o1 << 16),
                               (unsigned)o2 | ((unsigned)o3 << 16));
            }
        }
        #pragma unroll
        for (int t = 0; t < 2; t++)
            d[t][kb] = *(const s8v*)&as_[wave][t * 16 + lc][quad * 8];
    }
    #pragma unroll
    for (int t = 0; t < 2; t++) {
        d[t][3] = dh[t][0]; d[t][4] = dh[t][1]; d[t][5] = dh[t][2];
    }

    // ---- Stage 3: gate GEMM (LDS weights, this half's 3 jb) + epilogue ----
    for (int jbl = 0; jbl < 3; jbl++) {
        int jb = half * 3 + jbl;
        // h_old (bf16) at this lane's OUTPUT position: plane jb, 8B, L1-hot
        uint2 hu[2];
        #pragma unroll
        for (int t = 0; t < 2; t++) {
            if (val[t])
                hu[t] = *(const uint2*)(hbf_prev + (size_t)jb * PLE +
                                        (size_t)((nT0 + t) * 16 + lc) * 16 + quad * 4);
            else
                hu[t] = make_uint2(0u, 0u);
        }
        f4v acc[2][4] = {};
        const unsigned short* wj = lw + (size_t)jbl * 18 * 512 + (size_t)lane * 8;
        // g = 0 (r): full K
        #pragma unroll
        for (int ks = 0; ks < 6; ks++) {
            s8v w = *(const s8v*)(wj + ks * 512);
            acc[0][0] = __builtin_amdgcn_mfma_f32_16x16x32_bf16(w, d[0][ks], acc[0][0], 0, 0, 0);
            acc[1][0] = __builtin_amdgcn_mfma_f32_16x16x32_bf16(w, d[1][ks], acc[1][0], 0, 0, 0);
        }
        // g = 1 (z): full K
        #pragma unroll
        for (int ks = 0; ks < 6; ks++) {
            s8v w = *(const s8v*)(wj + (6 + ks) * 512);
            acc[0][1] = __builtin_amdgcn_mfma_f32_16x16x32_bf16(w, d[0][ks], acc[0][1], 0, 0, 0);
            acc[1][1] = __builtin_amdgcn_mfma_f32_16x16x32_bf16(w, d[1][ks], acc[1][1], 0, 0, 0);
        }
        // g = 2 (i_n, agg side ks 0..2) and g = 3 (h_n, h side ks 3..5)
        #pragma unroll
        for (int ks = 0; ks < 6; ks++) {
            s8v w = *(const s8v*)(wj + (12 + ks) * 512);
            int g = (ks < 3) ? 2 : 3;
            acc[0][g] = __builtin_amdgcn_mfma_f32_16x16x32_bf16(w, d[0][ks], acc[0][g], 0, 0, 0);
            acc[1][g] = __builtin_amdgcn_mfma_f32_16x16x32_bf16(w, d[1][ks], acc[1][g], 0, 0, 0);
        }
        const float* bp = bs + jb * 16 + quad * 4;
        float4 br  = *(const float4*)(bp);
        float4 bz  = *(const float4*)(bp + 96);
        float4 bin = *(const float4*)(bp + 192);
        float4 bhn = *(const float4*)(bp + 288);
        float brv[4]  = {br.x, br.y, br.z, br.w};
        float bzv[4]  = {bz.x, bz.y, bz.z, bz.w};
        float binv[4] = {bin.x, bin.y, bin.z, bin.w};
        float bhnv[4] = {bhn.x, bhn.y, bhn.z, bhn.w};
        #pragma unroll
        for (int t = 0; t < 2; t++) {
            if (!val[t]) continue;
            int node = (nT0 + t) * 16 + lc;
            float hv[4];
            hv[0] = bf2f((unsigned short)(hu[t].x & 0xFFFF));
            hv[1] = bf2f((unsigned short)(hu[t].x >> 16));
            hv[2] = bf2f((unsigned short)(hu[t].y & 0xFFFF));
            hv[3] = bf2f((unsigned short)(hu[t].y >> 16));
            float out[4];
            #pragma unroll
            for (int i = 0; i < 4; i++) {
                float rg = sigmoidf_(acc[t][0][i] + brv[i]);
                float zg = sigmoidf_(acc[t][1][i] + bzv[i]);
                float nn = tanhf_(acc[t][2][i] + binv[i] + rg * (acc[t][3][i] + bhnv[i]));
                out[i] = (1.f - zg) * nn + zg * hv[i];
            }
            unsigned short q0 = f2bf(out[0]), q1_ = f2bf(out[1]);
            unsigned short q2_ = f2bf(out[2]), q3 = f2bf(out[3]);
            // plane store: wave covers 16 nodes x 32B = 512B contiguous
            *(uint2*)(hbf_next + (size_t)jb * PLE + (size_t)node * 16 + quad * 4) =
                make_uint2((unsigned)q0 | ((unsigned)q1_ << 16),
                           (unsigned)q2_ | ((unsigned)q3 << 16));
            if (writeH) {
                float* hp = h + (size_t)node * 96 + jb * 16 + quad * 4;
                *(float4*)hp = make_float4(out[0], out[1], out[2], out[3]);
            }
        }
    }
}

// ---------------------------------------------------------------------------
// Mean pool via sorted-batch segments: one block per graph, no atomics.
// ---------------------------------------------------------------------------
__global__ __launch_bounds__(128) void pool_csr_k(
    const float* __restrict__ h, const int* __restrict__ rpb, float* __restrict__ g)
{
    int b = blockIdx.x;
    int j = threadIdx.x;
    if (j >= 96) return;
    int n0 = rpb[b], n1 = rpb[b + 1];
    float s = 0.f;
    for (int n = n0; n < n1; n++) s += fmaxf(h[(size_t)n * 96 + j], 0.f);
    float c = (float)(n1 - n0);
    g[(size_t)b * 96 + j] = s / fmaxf(c, 1.f);
}

__global__ void feat_k(const float* __restrict__ g1, const float* __restrict__ g2,
                       const float* __restrict__ g3, float* __restrict__ feat)
{
    int idx = blockIdx.x * 256 + threadIdx.x;
    if (idx >= BB * HH) return;
    int b = idx / HH, j = idx % HH;
    float a = g1[idx], bb = g2[idx], c = g3[idx];
    float* f = feat + (size_t)b * 384;
    f[j]       = a;
    f[96 + j]  = bb;
    f[192 + j] = c;
    f[288 + j] = a * bb * c;
}

// ---------------------------------------------------------------------------
// MLP GEMM v2: C[M,N] = relu(bf16(A[M,K]) @ Bp + bias).
// grid (N/128, M/16); 4 waves share the same 16 A-rows, each owns a 32-col
// strip -> high block concurrency for latency hiding.
// ---------------------------------------------------------------------------
__global__ __launch_bounds__(256) void gemm_mlp_mfma(
    const float* __restrict__ A, const unsigned short* __restrict__ Bp,
    const float* __restrict__ bias, float* __restrict__ C,
    int K, int N, int doRelu)
{
    int wave = threadIdx.x >> 6;
    int lane = threadIdx.x & 63;
    int quad = lane >> 4;
    int lc   = lane & 15;
    int rowA = blockIdx.y * 16 + lc;
    int colb = blockIdx.x * 128 + wave * 32;

    f4v acc[2] = {};
    for (int ks = 0; ks < K / 32; ks++) {
        s8v a = load_bf8(A + (size_t)rowA * K + ks * 32 + quad * 8);
        #pragma unroll
        for (int t = 0; t < 2; t++) {
            int n = colb + t * 16 + lc;
            s8v b = *(const s8v*)(Bp + ((size_t)(ks * N + n) * 4 + quad) * 8);
            acc[t] = __builtin_amdgcn_mfma_f32_16x16x32_bf16(a, b, acc[t], 0, 0, 0);
        }
    }
    int rowD = blockIdx.y * 16 + quad * 4;
    #pragma unroll
    for (int t = 0; t < 2; t++) {
        int n = colb + t * 16 + lc;
        float bv = bias[n];
        #pragma unroll
        for (int r = 0; r < 4; r++) {
            float v = acc[t][r] + bv;
            if (doRelu) v = fmaxf(v, 0.f);
            C[(size_t)(rowD + r) * N + n] = v;
        }
    }
}

// fc3: one wave per graph, shuffle reduction.
__global__ __launch_bounds__(256) void fc3_k(const float* __restrict__ t2,
                                             const float* __restrict__ w,
                                             const float* __restrict__ bias,
                                             float* __restrict__ out)
{
    int wave = threadIdx.x >> 6;
    int lane = threadIdx.x & 63;
    int b = blockIdx.x * 4 + wave;
    const float* row = t2 + (size_t)b * 384;
    float a0 = 0.f, a1 = 0.f, a2 = 0.f;
    #pragma unroll
    for (int kk = 0; kk < 6; kk++) {
        int k = kk * 64 + lane;
        float x = row[k];
        a0 += x * w[k * 3 + 0];
        a1 += x * w[k * 3 + 1];
        a2 += x * w[k * 3 + 2];
    }
    #pragma unroll
    for (int off = 32; off > 0; off >>= 1) {
        a0 += __shfl_down(a0, off);
        a1 += __shfl_down(a1, off);
        a2 += __shfl_down(a2, off);
    }
    if (lane == 0) {
        out[b * 3 + 0] = a0 + bias[0];
        out[b * 3 + 1] = a1 + bias[1];
        out[b * 3 + 2] = a2 + bias[2];
    }
}

extern "C" void kernel_launch(void* const* d_in, const int* in_sizes, int n_in,
                              void* d_out, int out_size, void* d_ws, size_t ws_size,
                              hipStream_t stream)
{
    // Workspace (floats). Total ~50.1M f ≈ 200 MB (237 MB proven safe).
    float* ws    = (float*)d_ws;
    float* h     = ws;                               // 19,200,000 (last-layer only)
    float* hbfAF = h + (size_t)NN_ * HH;             //  9,600,000 (19.2M bf16)
    float* hbfBF = hbfAF + (size_t)NN_ * HH / 2;     //  9,600,000 (19.2M bf16)
    float* aggF  = hbfBF + (size_t)NN_ * HH / 2;     //  9,600,000 (19.2M bf16)
    float* wpF   = aggF + (size_t)NN_ * HH / 2;      //     27,648
    float* wgpF  = wpF + 27648;                      //     36,864 (compact uses 27,648)
    float* fc1pF = wgpF + 36864;                     //    294,912 (589,824 bf16)
    float* fc2pF = fc1pF + 294912;                   //    294,912
    float* g3    = fc2pF + 294912;                   //  1,179,648
    int*   rp    = (int*)(g3 + 3 * (size_t)BB * HH); //    200,064 ints
    int*   srcs  = rp + 200064;                      //    400,000 ints
    int*   deg   = srcs + 400000;                    //    200,000 ints
    int*   cur   = deg + 200000;                     //    200,000 ints
    int*   bsum  = cur + 200000;                     //        256 ints
    int*   rpb   = bsum + 256;                       //      4,097 ints
    float* bs    = (float*)(rpb + 4097) + 1;         //        384 f (16B-aligned region)

    unsigned short* hbfA = (unsigned short*)hbfAF;
    unsigned short* hbfB = (unsigned short*)hbfBF;
    unsigned short* agg  = (unsigned short*)aggF;
    unsigned short* Wp   = (unsigned short*)wpF;
    unsigned short* Wgc  = (unsigned short*)wgpF;
    unsigned short* fc1p = (unsigned short*)fc1pF;
    unsigned short* fc2p = (unsigned short*)fc2pF;

    // MLP temps alias h (dead after pooling)
    float* feat = h;
    float* t1   = h + 2 * 1024 * 1024;
    float* t2   = h + 9 * 1024 * 1024;

    for (int c = 0; c < 3; c++) {
        const float* x   = (const float*)d_in[c * 8 + 0];
        const int*   ei  = (const int*)  d_in[c * 8 + 1];
        const int*   bat = (const int*)  d_in[c * 8 + 2];
        const float* W   = (const float*)d_in[c * 8 + 3];
        const float* wih = (const float*)d_in[c * 8 + 4];
        const float* whh = (const float*)d_in[c * 8 + 5];
        const float* bih = (const float*)d_in[c * 8 + 6];
        const float* bhh = (const float*)d_in[c * 8 + 7];

        // CSR build (once per component, reused for all 6 layers)
        hipMemsetAsync(deg, 0, NN_ * sizeof(int), stream);
        deg_k<<<cdiv(EE_, 256), 256, 0, stream>>>(ei, deg);
        scan1_k<<<NB_SCAN, SCAN_B, 0, stream>>>(deg, rp, bsum);
        scan2_k<<<1, 256, 0, stream>>>(bsum);
        scan3_k<<<cdiv(NN_, 256), 256, 0, stream>>>(rp, bsum, cur);
        fill_k<<<cdiv(EE_, 256), 256, 0, stream>>>(ei, cur, srcs);
        brp_k<<<cdiv(NN_, 256), 256, 0, stream>>>(bat, rpb);

        packWp_k<<<cdiv(LL * 6 * 3 * 64 * 8, 256), 256, 0, stream>>>(W, Wp);
        packWgc_k<<<cdiv(6 * 18 * 64 * 8, 256), 256, 0, stream>>>(wih, whh, Wgc);
        bpack_k<<<1, 128, 0, stream>>>(bih, bhh, bs);
        pad_k<<<cdiv(6 * PLE, 256), 256, 0, stream>>>(x, hbfA);

        unsigned short* pb[2] = {hbfA, hbfB};
        for (int l = 0; l < LL; l++) {
            agg_k<<<NN_ / 64, 128, 0, stream>>>(rp, srcs, pb[l & 1], agg);
            gru_k<<<dim3(cdiv(NT_, 16), 2), 512, 0, stream>>>(
                agg, Wp + (size_t)l * 9216, Wgc, bs, pb[l & 1], pb[(l + 1) & 1],
                h, (l == LL - 1) ? 1 : 0);
        }

        pool_csr_k<<<BB, 128, 0, stream>>>(h, rpb, g3 + (size_t)c * BB * HH);
    }

    const float* fc1_w = (const float*)d_in[24];
    const float* fc1_b = (const float*)d_in[25];
    const float* fc2_w = (const float*)d_in[26];
    const float* fc2_b = (const float*)d_in[27];
    const float* fc3_w = (const float*)d_in[28];
    const float* fc3_b = (const float*)d_in[29];

    packB_k<<<cdiv(384 * 1536, 256), 256, 0, stream>>>(fc1_w, fc1p, 384, 1536);
    packB_k<<<cdiv(1536 * 384, 256), 256, 0, stream>>>(fc2_w, fc2p, 1536, 384);

    feat_k<<<cdiv(BB * HH, 256), 256, 0, stream>>>(
        g3, g3 + (size_t)BB * HH, g3 + 2 * (size_t)BB * HH, feat);
    gemm_mlp_mfma<<<dim3(1536 / 128, BB / 16), 256, 0, stream>>>(
        feat, fc1p, fc1_b, t1, 384, 1536, 1);
    gemm_mlp_mfma<<<dim3(384 / 128, BB / 16), 256, 0, stream>>>(
        t1, fc2p, fc2_b, t2, 1536, 384, 1);
    fc3_k<<<BB / 4, 256, 0, stream>>>(t2, fc3_w, fc3_b, (float*)d_out);
}

// Round 11
// 2662.180 us; speedup vs baseline: 1.2054x; 1.2054x over previous
//
#include <hip/hip_runtime.h>
#include <math.h>

#define NN_ 200000
#define EE_ 400000
#define HH  96
#define LL  6
#define BB  4096
#define NT_ 12500     // node tiles of 16
#define SCAN_B 1024
#define NB_SCAN 196   // cdiv(200000, 1024)

typedef short s8v __attribute__((ext_vector_type(8)));
typedef float f4v __attribute__((ext_vector_type(4)));
typedef float f2v __attribute__((ext_vector_type(2)));

static inline int cdiv(int a, int b) { return (a + b - 1) / b; }

__device__ __forceinline__ float sigmoidf_(float x) { return 1.0f / (1.0f + __expf(-x)); }
__device__ __forceinline__ float tanhf_(float x) { return 1.0f - 2.0f / (__expf(2.0f * x) + 1.0f); }
__device__ __forceinline__ unsigned short f2bf(float x) {
    unsigned u = __float_as_uint(x);
    unsigned r = u + 0x7FFF + ((u >> 16) & 1);   // RNE
    return (unsigned short)(r >> 16);
}
__device__ __forceinline__ float bf2f(unsigned short u) {
    return __uint_as_float(((unsigned)u) << 16);
}
// load 8 consecutive fp32 and convert to a bf16x8 MFMA fragment (in-register)
__device__ __forceinline__ s8v load_bf8(const float* __restrict__ p) {
    float4 v0 = *(const float4*)p;
    float4 v1 = *(const float4*)(p + 4);
    s8v r;
    r[0] = (short)f2bf(v0.x); r[1] = (short)f2bf(v0.y);
    r[2] = (short)f2bf(v0.z); r[3] = (short)f2bf(v0.w);
    r[4] = (short)f2bf(v1.x); r[5] = (short)f2bf(v1.y);
    r[6] = (short)f2bf(v1.z); r[7] = (short)f2bf(v1.w);
    return r;
}

// bf16-pair accumulate: u holds 2 bf16; low elem -> a[0], high elem -> a[1]
__device__ __forceinline__ void accu_(f2v& a, unsigned u) {
    a[0] += __uint_as_float(u << 16);
    a[1] += __uint_as_float(u & 0xFFFF0000u);
}
__device__ __forceinline__ void acc_row_(f2v* ag2, const uint4& u, int ks) {
    accu_(ag2[ks * 4 + 0], u.x); accu_(ag2[ks * 4 + 1], u.y);
    accu_(ag2[ks * 4 + 2], u.z); accu_(ag2[ks * 4 + 3], u.w);
}

// ---------------------------------------------------------------------------
// MLP weight pack (B-operand fragment order, read from global):
// Bp[((k>>5)*N + n)*32 + ((k>>3)&3)*8 + (k&7)] = bf16(B[k*N + n])
// ---------------------------------------------------------------------------
__global__ void packB_k(const float* __restrict__ B, unsigned short* __restrict__ Bp,
                        int K, int N)
{
    int idx = blockIdx.x * 256 + threadIdx.x;
    if (idx >= K * N) return;
    int k = idx / N, n = idx % N;
    Bp[(((size_t)(k >> 5) * N + n) * 4 + ((k >> 3) & 3)) * 8 + (k & 7)] = f2bf(B[idx]);
}

// ---------------------------------------------------------------------------
// Wp pack, weight-stationary A-operand order:
// offset = (((l*6 + jb)*3 + ks)*64 + lane)*8 + j
//   holds  W[l][k = ks*32 + (lane>>4)*8 + j][n = jb*16 + (lane&15)]
// ---------------------------------------------------------------------------
__global__ void packWp_k(const float* __restrict__ W, unsigned short* __restrict__ Wp)
{
    int idx = blockIdx.x * 256 + threadIdx.x;
    if (idx >= LL * 6 * 3 * 64 * 8) return;
    int j    = idx & 7;
    int lane = (idx >> 3) & 63;
    int rest = idx >> 9;
    int ks = rest % 3;
    int jb = (rest / 3) % 6;
    int l  = rest / 18;
    int quad = lane >> 4, lc = lane & 15;
    int k = ks * 32 + quad * 8 + j;
    int n = jb * 16 + lc;
    Wp[idx] = f2bf(W[(size_t)l * 9216 + (size_t)k * 96 + n]);
}

// ---------------------------------------------------------------------------
// Wgc pack: COMPACT gate weights [6 jb][18 ksb][64 lane][8 j]  (zeros removed)
//   ksb 0..5   -> g=0 (r), ks=ksb      (full K: agg then h)
//   ksb 6..11  -> g=1 (z), ks=ksb-6
//   ksb 12..14 -> g=2 (i_n), ks=ksb-12 (k<96: agg side only)
//   ksb 15..17 -> g=3 (h_n), ks=ksb-12 -> 3..5 (k>=96: h side only)
// value at k = ks*32 + quad*8 + j, n = g*96 + jb*16 + lc
// ---------------------------------------------------------------------------
__global__ void packWgc_k(const float* __restrict__ wih, const float* __restrict__ whh,
                          unsigned short* __restrict__ Wgc)
{
    int idx = blockIdx.x * 256 + threadIdx.x;
    if (idx >= 6 * 18 * 64 * 8) return;
    int j    = idx & 7;
    int lane = (idx >> 3) & 63;
    int rest = idx >> 9;          // < 108
    int ksb = rest % 18;
    int jb  = rest / 18;
    int quad = lane >> 4, lc = lane & 15;
    int g, ks;
    if (ksb < 6)       { g = 0; ks = ksb; }
    else if (ksb < 12) { g = 1; ks = ksb - 6; }
    else if (ksb < 15) { g = 2; ks = ksb - 12; }
    else               { g = 3; ks = ksb - 12; }   // 3..5
    int k = ks * 32 + quad * 8 + j;
    int n = g * 96 + jb * 16 + lc;
    float v;
    if (n < 192) {
        v = (k < 96) ? wih[(size_t)n * 96 + k] : whh[(size_t)n * 96 + (k - 96)];
    } else if (n < 288) {
        int jj = n - 192;
        v = wih[(size_t)(192 + jj) * 96 + k];          // g=2: k<96 guaranteed
    } else {
        int jj = n - 288;
        v = whh[(size_t)(192 + jj) * 96 + (k - 96)];   // g=3: k>=96 guaranteed
    }
    Wgc[idx] = f2bf(v);
}

// combined bias pack: bs[0..95]=bih_r+bhh_r, [96..191]=bih_z+bhh_z,
// [192..287]=bih_n, [288..383]=bhh_n
__global__ void bpack_k(const float* __restrict__ bih, const float* __restrict__ bhh,
                        float* __restrict__ bs)
{
    int j = threadIdx.x;
    if (j >= 96) return;
    bs[j]        = bih[j] + bhh[j];
    bs[96 + j]   = bih[96 + j] + bhh[96 + j];
    bs[192 + j]  = bih[192 + j];
    bs[288 + j]  = bhh[192 + j];
}

__global__ void pad_k(const float* __restrict__ x, unsigned short* __restrict__ hbf)
{
    int idx = blockIdx.x * 256 + threadIdx.x;
    if (idx >= NN_ * HH) return;
    int n = idx / HH, j = idx % HH;
    float v = (j < 32) ? x[n * 32 + j] : 0.f;
    hbf[idx] = f2bf(v);
}

// --------------------------- CSR build (once per component) -----------------
__global__ void deg_k(const int* __restrict__ ei, int* __restrict__ deg)
{
    int e = blockIdx.x * 256 + threadIdx.x;
    if (e >= EE_) return;
    atomicAdd(&deg[ei[EE_ + e]], 1);
}

__global__ __launch_bounds__(SCAN_B) void scan1_k(
    const int* __restrict__ deg, int* __restrict__ rp, int* __restrict__ bsum)
{
    __shared__ int sh[SCAN_B];
    int i = blockIdx.x * SCAN_B + threadIdx.x;
    int v = (i < NN_) ? deg[i] : 0;
    sh[threadIdx.x] = v;
    __syncthreads();
    for (int off = 1; off < SCAN_B; off <<= 1) {
        int t = (threadIdx.x >= off) ? sh[threadIdx.x - off] : 0;
        __syncthreads();
        sh[threadIdx.x] += t;
        __syncthreads();
    }
    if (i < NN_) rp[i] = sh[threadIdx.x] - v;     // exclusive within block
    if (threadIdx.x == SCAN_B - 1) bsum[blockIdx.x] = sh[threadIdx.x];
}

__global__ __launch_bounds__(256) void scan2_k(int* __restrict__ bsum)
{
    __shared__ int sh[256];
    int v = (threadIdx.x < NB_SCAN) ? bsum[threadIdx.x] : 0;
    sh[threadIdx.x] = v;
    __syncthreads();
    for (int off = 1; off < 256; off <<= 1) {
        int t = (threadIdx.x >= off) ? sh[threadIdx.x - off] : 0;
        __syncthreads();
        sh[threadIdx.x] += t;
        __syncthreads();
    }
    if (threadIdx.x < NB_SCAN) bsum[threadIdx.x] = sh[threadIdx.x] - v;  // exclusive
}

__global__ void scan3_k(int* __restrict__ rp, const int* __restrict__ bsum,
                        int* __restrict__ cur)
{
    int i = blockIdx.x * 256 + threadIdx.x;
    if (i < NN_) {
        int r = rp[i] + bsum[i / SCAN_B];
        rp[i] = r;
        cur[i] = r;
    }
    if (i == 0) rp[NN_] = EE_;
}

// srcs stores BYTE offsets into the bf16 hbf rows (s * 192).
__global__ void fill_k(const int* __restrict__ ei, int* __restrict__ cur,
                       int* __restrict__ srcs)
{
    int e = blockIdx.x * 256 + threadIdx.x;
    if (e >= EE_) return;
    int s = ei[e];
    int d = ei[EE_ + e];
    int pos = atomicAdd(&cur[d], 1);
    srcs[pos] = s * 192;
}

// batch row pointers: batch[] is sorted, detect segment boundaries.
__global__ void brp_k(const int* __restrict__ bat, int* __restrict__ rpb)
{
    int i = blockIdx.x * 256 + threadIdx.x;
    if (i >= NN_) return;
    int b = bat[i];
    if (i == 0) {
        for (int q = 0; q <= b; q++) rpb[q] = 0;
    } else {
        int p = bat[i - 1];
        for (int q = p + 1; q <= b; q++) rpb[q] = i;
    }
    if (i == NN_ - 1) {
        for (int q = b + 1; q <= BB; q++) rpb[q] = NN_;
    }
}

// ---------------------------------------------------------------------------
// Phase A: aggbf[n] = sum over in-edges of hbf[src]  (bf16 out, fp32 acc).
// ---------------------------------------------------------------------------
__global__ __launch_bounds__(128) void agg_k(
    const int* __restrict__ rp, const int* __restrict__ srcs,
    const unsigned short* __restrict__ hbf,
    unsigned short* __restrict__ aggbf)
{
    int tid  = threadIdx.x;
    int wave = tid >> 6;
    int lane = tid & 63;
    int quad = lane >> 4;
    int lc   = lane & 15;
    int nT0  = blockIdx.x * 4 + wave * 2;

    const char* gbase = (const char*)hbf + quad * 16;

    #pragma unroll
    for (int t = 0; t < 2; t++) {
        int node = (nT0 + t) * 16 + lc;
        f2v ag2[12];
        #pragma unroll
        for (int i = 0; i < 12; i++) ag2[i] = (f2v){0.f, 0.f};
        int e = rp[node], e1 = rp[node + 1];
        for (; e < e1; e++) {
            const char* r = gbase + srcs[e];
            uint4 u0 = *(const uint4*)r;
            uint4 u1 = *(const uint4*)(r + 64);
            uint4 u2 = *(const uint4*)(r + 128);
            acc_row_(ag2, u0, 0); acc_row_(ag2, u1, 1); acc_row_(ag2, u2, 2);
        }
        #pragma unroll
        for (int ks = 0; ks < 3; ks++) {
            unsigned q0 = (unsigned)f2bf(ag2[ks * 4 + 0][0]) | ((unsigned)f2bf(ag2[ks * 4 + 0][1]) << 16);
            unsigned q1 = (unsigned)f2bf(ag2[ks * 4 + 1][0]) | ((unsigned)f2bf(ag2[ks * 4 + 1][1]) << 16);
            unsigned q2 = (unsigned)f2bf(ag2[ks * 4 + 2][0]) | ((unsigned)f2bf(ag2[ks * 4 + 2][1]) << 16);
            unsigned q3 = (unsigned)f2bf(ag2[ks * 4 + 3][0]) | ((unsigned)f2bf(ag2[ks * 4 + 3][1]) << 16);
            *(uint4*)(aggbf + (size_t)node * 96 + ks * 32 + quad * 8) =
                make_uint4(q0, q1, q2, q3);
        }
    }
}

// ---------------------------------------------------------------------------
// Phase B v8: GRU update, bf16 state, 3-part jb split (2 jb/block) with
// LDS UNION: as_ (Stage-1 transpose, 18,432B) and lw (2-jb weights,
// 36,864B) share one 36,864B buffer (time-disjoint: as_ dead after d[]
// extraction, weights staged after a barrier).
// LDS 36,864B -> 4 blocks/CU (32 waves/CU) vs R7's 2 -> latency hiding 2x.
// 512 thr (8 waves); grid (cdiv(NT_,16), 3); part = blockIdx.y owns
// jb { 2p, 2p+1 }. h_old bf16 from hbf_prev; fp32 h written on last layer.
// ---------------------------------------------------------------------------
__global__ __launch_bounds__(512) void gru_k(
    const unsigned short* __restrict__ aggbf,
    const unsigned short* __restrict__ Wp,    // this layer: [6][3][64][8] (global)
    const unsigned short* __restrict__ Wgc,   // compact [6][18][64][8]
    const float* __restrict__ bs,
    const unsigned short* __restrict__ hbf_prev,
    unsigned short* __restrict__ hbf_next,
    float* __restrict__ h,
    int writeH)
{
    __shared__ unsigned short buf[18432];         // 36,864 B (as_ then lw)
    int tid  = threadIdx.x;
    int part = blockIdx.y;

    int wave = tid >> 6;
    int lane = tid & 63;
    int quad = lane >> 4;
    int lc   = lane & 15;
    int nT0  = blockIdx.x * 16 + wave * 2;

    bool val[2];
    val[0] = (nT0 + 0) < NT_;
    val[1] = (nT0 + 1) < NT_;

    s8v z8;
    #pragma unroll
    for (int q = 0; q < 8; q++) z8[q] = 0;

    // coalesced fragment loads: gathered messages + own-row h (bf16, prev)
    s8v hg[2][3], dh[2][3];
    #pragma unroll
    for (int t = 0; t < 2; t++) {
        int node = (nT0 + t) * 16 + lc;
        #pragma unroll
        for (int ks = 0; ks < 3; ks++) {
            if (val[t]) {
                hg[t][ks] = *(const s8v*)(aggbf    + (size_t)node * 96 + ks * 32 + quad * 8);
                dh[t][ks] = *(const s8v*)(hbf_prev + (size_t)node * 96 + ks * 32 + quad * 8);
            } else {
                hg[t][ks] = z8;
                dh[t][ks] = z8;
            }
        }
    }

    // ---- Stage 1: agg@W (ALL 96 cols), wave-local transpose in buf[as_] ----
    unsigned short* asw = buf + wave * 32 * 36;   // wave-private [32][36]
    s8v d[2][6];
    #pragma unroll
    for (int kb = 0; kb < 3; kb++) {
        #pragma unroll
        for (int jj = 0; jj < 2; jj++) {
            int jb = kb * 2 + jj;
            f4v a1[2] = {};
            #pragma unroll
            for (int ks = 0; ks < 3; ks++) {
                s8v w = *(const s8v*)(Wp + ((size_t)(jb * 3 + ks) * 64 + lane) * 8);
                a1[0] = __builtin_amdgcn_mfma_f32_16x16x32_bf16(w, hg[0][ks], a1[0], 0, 0, 0);
                a1[1] = __builtin_amdgcn_mfma_f32_16x16x32_bf16(w, hg[1][ks], a1[1], 0, 0, 0);
            }
            #pragma unroll
            for (int t = 0; t < 2; t++) {
                unsigned short o0 = f2bf(a1[t][0]), o1 = f2bf(a1[t][1]);
                unsigned short o2 = f2bf(a1[t][2]), o3 = f2bf(a1[t][3]);
                *(uint2*)&asw[(size_t)(t * 16 + lc) * 36 + jj * 16 + quad * 4] =
                    make_uint2((unsigned)o0 | ((unsigned)o1 << 16),
                               (unsigned)o2 | ((unsigned)o3 << 16));
            }
        }
        #pragma unroll
        for (int t = 0; t < 2; t++)
            d[t][kb] = *(const s8v*)&asw[(size_t)(t * 16 + lc) * 36 + quad * 8];
    }
    #pragma unroll
    for (int t = 0; t < 2; t++) {
        d[t][3] = dh[t][0]; d[t][4] = dh[t][1]; d[t][5] = dh[t][2];
    }

    // ---- stage this part's 2-jb weights into buf (as_ now dead) ----
    __syncthreads();
    {
        const uint4* src = (const uint4*)Wgc + (size_t)part * 2304;
        uint4* dst = (uint4*)buf;
        #pragma unroll
        for (int it = 0; it < 5; it++) {
            int i = it * 512 + tid;
            if (i < 2304) dst[i] = src[i];
        }
    }
    __syncthreads();

    // ---- Stage 3: gate GEMM (LDS weights, 2 jb) + epilogue ----
    for (int jbl = 0; jbl < 2; jbl++) {
        int jb = part * 2 + jbl;
        // h_old (bf16) at this lane's OUTPUT position: 8B, L1-hot
        uint2 hu[2];
        #pragma unroll
        for (int t = 0; t < 2; t++) {
            if (val[t])
                hu[t] = *(const uint2*)(hbf_prev + (size_t)((nT0 + t) * 16 + lc) * 96 + jb * 16 + quad * 4);
            else
                hu[t] = make_uint2(0u, 0u);
        }
        f4v acc[2][4] = {};
        const unsigned short* wj = buf + (size_t)jbl * 18 * 512 + (size_t)lane * 8;
        // g = 0 (r): full K
        #pragma unroll
        for (int ks = 0; ks < 6; ks++) {
            s8v w = *(const s8v*)(wj + ks * 512);
            acc[0][0] = __builtin_amdgcn_mfma_f32_16x16x32_bf16(w, d[0][ks], acc[0][0], 0, 0, 0);
            acc[1][0] = __builtin_amdgcn_mfma_f32_16x16x32_bf16(w, d[1][ks], acc[1][0], 0, 0, 0);
        }
        // g = 1 (z): full K
        #pragma unroll
        for (int ks = 0; ks < 6; ks++) {
            s8v w = *(const s8v*)(wj + (6 + ks) * 512);
            acc[0][1] = __builtin_amdgcn_mfma_f32_16x16x32_bf16(w, d[0][ks], acc[0][1], 0, 0, 0);
            acc[1][1] = __builtin_amdgcn_mfma_f32_16x16x32_bf16(w, d[1][ks], acc[1][1], 0, 0, 0);
        }
        // g = 2 (i_n, agg side ks 0..2) and g = 3 (h_n, h side ks 3..5)
        #pragma unroll
        for (int ks = 0; ks < 6; ks++) {
            s8v w = *(const s8v*)(wj + (12 + ks) * 512);
            int g = (ks < 3) ? 2 : 3;
            acc[0][g] = __builtin_amdgcn_mfma_f32_16x16x32_bf16(w, d[0][ks], acc[0][g], 0, 0, 0);
            acc[1][g] = __builtin_amdgcn_mfma_f32_16x16x32_bf16(w, d[1][ks], acc[1][g], 0, 0, 0);
        }
        const float* bp = bs + jb * 16 + quad * 4;
        float4 br  = *(const float4*)(bp);
        float4 bz  = *(const float4*)(bp + 96);
        float4 bin = *(const float4*)(bp + 192);
        float4 bhn = *(const float4*)(bp + 288);
        float brv[4]  = {br.x, br.y, br.z, br.w};
        float bzv[4]  = {bz.x, bz.y, bz.z, bz.w};
        float binv[4] = {bin.x, bin.y, bin.z, bin.w};
        float bhnv[4] = {bhn.x, bhn.y, bhn.z, bhn.w};
        #pragma unroll
        for (int t = 0; t < 2; t++) {
            if (!val[t]) continue;
            int node = (nT0 + t) * 16 + lc;
            float hv[4];
            hv[0] = bf2f((unsigned short)(hu[t].x & 0xFFFF));
            hv[1] = bf2f((unsigned short)(hu[t].x >> 16));
            hv[2] = bf2f((unsigned short)(hu[t].y & 0xFFFF));
            hv[3] = bf2f((unsigned short)(hu[t].y >> 16));
            float out[4];
            #pragma unroll
            for (int i = 0; i < 4; i++) {
                float rg = sigmoidf_(acc[t][0][i] + brv[i]);
                float zg = sigmoidf_(acc[t][1][i] + bzv[i]);
                float nn = tanhf_(acc[t][2][i] + binv[i] + rg * (acc[t][3][i] + bhnv[i]));
                out[i] = (1.f - zg) * nn + zg * hv[i];
            }
            unsigned short q0 = f2bf(out[0]), q1 = f2bf(out[1]);
            unsigned short q2 = f2bf(out[2]), q3 = f2bf(out[3]);
            *(uint2*)(hbf_next + (size_t)node * 96 + jb * 16 + quad * 4) =
                make_uint2((unsigned)q0 | ((unsigned)q1 << 16),
                           (unsigned)q2 | ((unsigned)q3 << 16));
            if (writeH) {
                float* hp = h + (size_t)node * 96 + jb * 16 + quad * 4;
                *(float4*)hp = make_float4(out[0], out[1], out[2], out[3]);
            }
        }
    }
}

// ---------------------------------------------------------------------------
// Mean pool via sorted-batch segments: one block per graph, no atomics.
// ---------------------------------------------------------------------------
__global__ __launch_bounds__(128) void pool_csr_k(
    const float* __restrict__ h, const int* __restrict__ rpb, float* __restrict__ g)
{
    int b = blockIdx.x;
    int j = threadIdx.x;
    if (j >= 96) return;
    int n0 = rpb[b], n1 = rpb[b + 1];
    float s = 0.f;
    for (int n = n0; n < n1; n++) s += fmaxf(h[(size_t)n * 96 + j], 0.f);
    float c = (float)(n1 - n0);
    g[(size_t)b * 96 + j] = s / fmaxf(c, 1.f);
}

__global__ void feat_k(const float* __restrict__ g1, const float* __restrict__ g2,
                       const float* __restrict__ g3, float* __restrict__ feat)
{
    int idx = blockIdx.x * 256 + threadIdx.x;
    if (idx >= BB * HH) return;
    int b = idx / HH, j = idx % HH;
    float a = g1[idx], bb = g2[idx], c = g3[idx];
    float* f = feat + (size_t)b * 384;
    f[j]       = a;
    f[96 + j]  = bb;
    f[192 + j] = c;
    f[288 + j] = a * bb * c;
}

// ---------------------------------------------------------------------------
// MLP GEMM v2: C[M,N] = relu(bf16(A[M,K]) @ Bp + bias).
// grid (N/128, M/16); 4 waves share the same 16 A-rows, each owns a 32-col
// strip -> high block concurrency for latency hiding.
// ---------------------------------------------------------------------------
__global__ __launch_bounds__(256) void gemm_mlp_mfma(
    const float* __restrict__ A, const unsigned short* __restrict__ Bp,
    const float* __restrict__ bias, float* __restrict__ C,
    int K, int N, int doRelu)
{
    int wave = threadIdx.x >> 6;
    int lane = threadIdx.x & 63;
    int quad = lane >> 4;
    int lc   = lane & 15;
    int rowA = blockIdx.y * 16 + lc;
    int colb = blockIdx.x * 128 + wave * 32;

    f4v acc[2] = {};
    for (int ks = 0; ks < K / 32; ks++) {
        s8v a = load_bf8(A + (size_t)rowA * K + ks * 32 + quad * 8);
        #pragma unroll
        for (int t = 0; t < 2; t++) {
            int n = colb + t * 16 + lc;
            s8v b = *(const s8v*)(Bp + ((size_t)(ks * N + n) * 4 + quad) * 8);
            acc[t] = __builtin_amdgcn_mfma_f32_16x16x32_bf16(a, b, acc[t], 0, 0, 0);
        }
    }
    int rowD = blockIdx.y * 16 + quad * 4;
    #pragma unroll
    for (int t = 0; t < 2; t++) {
        int n = colb + t * 16 + lc;
        float bv = bias[n];
        #pragma unroll
        for (int r = 0; r < 4; r++) {
            float v = acc[t][r] + bv;
            if (doRelu) v = fmaxf(v, 0.f);
            C[(size_t)(rowD + r) * N + n] = v;
        }
    }
}

// fc3: one wave per graph, shuffle reduction.
__global__ __launch_bounds__(256) void fc3_k(const float* __restrict__ t2,
                                             const float* __restrict__ w,
                                             const float* __restrict__ bias,
                                             float* __restrict__ out)
{
    int wave = threadIdx.x >> 6;
    int lane = threadIdx.x & 63;
    int b = blockIdx.x * 4 + wave;
    const float* row = t2 + (size_t)b * 384;
    float a0 = 0.f, a1 = 0.f, a2 = 0.f;
    #pragma unroll
    for (int kk = 0; kk < 6; kk++) {
        int k = kk * 64 + lane;
        float x = row[k];
        a0 += x * w[k * 3 + 0];
        a1 += x * w[k * 3 + 1];
        a2 += x * w[k * 3 + 2];
    }
    #pragma unroll
    for (int off = 32; off > 0; off >>= 1) {
        a0 += __shfl_down(a0, off);
        a1 += __shfl_down(a1, off);
        a2 += __shfl_down(a2, off);
    }
    if (lane == 0) {
        out[b * 3 + 0] = a0 + bias[0];
        out[b * 3 + 1] = a1 + bias[1];
        out[b * 3 + 2] = a2 + bias[2];
    }
}

extern "C" void kernel_launch(void* const* d_in, const int* in_sizes, int n_in,
                              void* d_out, int out_size, void* d_ws, size_t ws_size,
                              hipStream_t stream)
{
    // Workspace (floats). Total ~50.1M f ≈ 200 MB (237 MB proven safe).
    float* ws    = (float*)d_ws;
    float* h     = ws;                               // 19,200,000 (last-layer only)
    float* hbfAF = h + (size_t)NN_ * HH;             //  9,600,000 (19.2M bf16)
    float* hbfBF = hbfAF + (size_t)NN_ * HH / 2;     //  9,600,000 (19.2M bf16)
    float* aggF  = hbfBF + (size_t)NN_ * HH / 2;     //  9,600,000 (19.2M bf16)
    float* wpF   = aggF + (size_t)NN_ * HH / 2;      //     27,648
    float* wgpF  = wpF + 27648;                      //     36,864 (compact uses 27,648)
    float* fc1pF = wgpF + 36864;                     //    294,912 (589,824 bf16)
    float* fc2pF = fc1pF + 294912;                   //    294,912
    float* g3    = fc2pF + 294912;                   //  1,179,648
    int*   rp    = (int*)(g3 + 3 * (size_t)BB * HH); //    200,064 ints
    int*   srcs  = rp + 200064;                      //    400,000 ints
    int*   deg   = srcs + 400000;                    //    200,000 ints
    int*   cur   = deg + 200000;                     //    200,000 ints
    int*   bsum  = cur + 200000;                     //        256 ints
    int*   rpb   = bsum + 256;                       //      4,097 ints
    float* bs    = (float*)(rpb + 4097) + 1;         //        384 f (16B-aligned region)

    unsigned short* hbfA = (unsigned short*)hbfAF;
    unsigned short* hbfB = (unsigned short*)hbfBF;
    unsigned short* agg  = (unsigned short*)aggF;
    unsigned short* Wp   = (unsigned short*)wpF;
    unsigned short* Wgc  = (unsigned short*)wgpF;
    unsigned short* fc1p = (unsigned short*)fc1pF;
    unsigned short* fc2p = (unsigned short*)fc2pF;

    // MLP temps alias h (dead after pooling)
    float* feat = h;
    float* t1   = h + 2 * 1024 * 1024;
    float* t2   = h + 9 * 1024 * 1024;

    for (int c = 0; c < 3; c++) {
        const float* x   = (const float*)d_in[c * 8 + 0];
        const int*   ei  = (const int*)  d_in[c * 8 + 1];
        const int*   bat = (const int*)  d_in[c * 8 + 2];
        const float* W   = (const float*)d_in[c * 8 + 3];
        const float* wih = (const float*)d_in[c * 8 + 4];
        const float* whh = (const float*)d_in[c * 8 + 5];
        const float* bih = (const float*)d_in[c * 8 + 6];
        const float* bhh = (const float*)d_in[c * 8 + 7];

        // CSR build (once per component, reused for all 6 layers)
        hipMemsetAsync(deg, 0, NN_ * sizeof(int), stream);
        deg_k<<<cdiv(EE_, 256), 256, 0, stream>>>(ei, deg);
        scan1_k<<<NB_SCAN, SCAN_B, 0, stream>>>(deg, rp, bsum);
        scan2_k<<<1, 256, 0, stream>>>(bsum);
        scan3_k<<<cdiv(NN_, 256), 256, 0, stream>>>(rp, bsum, cur);
        fill_k<<<cdiv(EE_, 256), 256, 0, stream>>>(ei, cur, srcs);
        brp_k<<<cdiv(NN_, 256), 256, 0, stream>>>(bat, rpb);

        packWp_k<<<cdiv(LL * 6 * 3 * 64 * 8, 256), 256, 0, stream>>>(W, Wp);
        packWgc_k<<<cdiv(6 * 18 * 64 * 8, 256), 256, 0, stream>>>(wih, whh, Wgc);
        bpack_k<<<1, 128, 0, stream>>>(bih, bhh, bs);
        pad_k<<<cdiv(NN_ * HH, 256), 256, 0, stream>>>(x, hbfA);

        unsigned short* pb[2] = {hbfA, hbfB};
        for (int l = 0; l < LL; l++) {
            agg_k<<<NN_ / 64, 128, 0, stream>>>(rp, srcs, pb[l & 1], agg);
            gru_k<<<dim3(cdiv(NT_, 16), 3), 512, 0, stream>>>(
                agg, Wp + (size_t)l * 9216, Wgc, bs, pb[l & 1], pb[(l + 1) & 1],
                h, (l == LL - 1) ? 1 : 0);
        }

        pool_csr_k<<<BB, 128, 0, stream>>>(h, rpb, g3 + (size_t)c * BB * HH);
    }

    const float* fc1_w = (const float*)d_in[24];
    const float* fc1_b = (const float*)d_in[25];
    const float* fc2_w = (const float*)d_in[26];
    const float* fc2_b = (const float*)d_in[27];
    const float* fc3_w = (const float*)d_in[28];
    const float* fc3_b = (const float*)d_in[29];

    packB_k<<<cdiv(384 * 1536, 256), 256, 0, stream>>>(fc1_w, fc1p, 384, 1536);
    packB_k<<<cdiv(1536 * 384, 256), 256, 0, stream>>>(fc2_w, fc2p, 1536, 384);

    feat_k<<<cdiv(BB * HH, 256), 256, 0, stream>>>(
        g3, g3 + (size_t)BB * HH, g3 + 2 * (size_t)BB * HH, feat);
    gemm_mlp_mfma<<<dim3(1536 / 128, BB / 16), 256, 0, stream>>>(
        feat, fc1p, fc1_b, t1, 384, 1536, 1);
    gemm_mlp_mfma<<<dim3(384 / 128, BB / 16), 256, 0, stream>>>(
        t1, fc2p, fc2_b, t2, 1536, 384, 1);
    fc3_k<<<BB / 4, 256, 0, stream>>>(t2, fc3_w, fc3_b, (float*)d_out);
}

// Round 12
// 2288.498 us; speedup vs baseline: 1.4022x; 1.1633x over previous
//
#include <hip/hip_runtime.h>
#include <math.h>

#define NN_ 200000
#define EE_ 400000
#define HH  96
#define LL  6
#define BB  4096
#define NT_ 12500     // node tiles of 16
#define SCAN_B 1024
#define NB_SCAN 196   // cdiv(200000, 1024)

typedef short s8v __attribute__((ext_vector_type(8)));
typedef float f4v __attribute__((ext_vector_type(4)));
typedef float f2v __attribute__((ext_vector_type(2)));

static inline int cdiv(int a, int b) { return (a + b - 1) / b; }

__device__ __forceinline__ float sigmoidf_(float x) { return 1.0f / (1.0f + __expf(-x)); }
__device__ __forceinline__ float tanhf_(float x) { return 1.0f - 2.0f / (__expf(2.0f * x) + 1.0f); }
__device__ __forceinline__ unsigned short f2bf(float x) {
    unsigned u = __float_as_uint(x);
    unsigned r = u + 0x7FFF + ((u >> 16) & 1);   // RNE
    return (unsigned short)(r >> 16);
}
__device__ __forceinline__ float bf2f(unsigned short u) {
    return __uint_as_float(((unsigned)u) << 16);
}
// load 8 consecutive fp32 and convert to a bf16x8 MFMA fragment (in-register)
__device__ __forceinline__ s8v load_bf8(const float* __restrict__ p) {
    float4 v0 = *(const float4*)p;
    float4 v1 = *(const float4*)(p + 4);
    s8v r;
    r[0] = (short)f2bf(v0.x); r[1] = (short)f2bf(v0.y);
    r[2] = (short)f2bf(v0.z); r[3] = (short)f2bf(v0.w);
    r[4] = (short)f2bf(v1.x); r[5] = (short)f2bf(v1.y);
    r[6] = (short)f2bf(v1.z); r[7] = (short)f2bf(v1.w);
    return r;
}

// bf16-pair accumulate: u holds 2 bf16; low elem -> a[0], high elem -> a[1]
__device__ __forceinline__ void accu_(f2v& a, unsigned u) {
    a[0] += __uint_as_float(u << 16);
    a[1] += __uint_as_float(u & 0xFFFF0000u);
}
__device__ __forceinline__ void acc_row_(f2v* ag2, const uint4& u, int ks) {
    accu_(ag2[ks * 4 + 0], u.x); accu_(ag2[ks * 4 + 1], u.y);
    accu_(ag2[ks * 4 + 2], u.z); accu_(ag2[ks * 4 + 3], u.w);
}

// ---------------------------------------------------------------------------
// MLP weight pack (B-operand fragment order, read from global):
// Bp[((k>>5)*N + n)*32 + ((k>>3)&3)*8 + (k&7)] = bf16(B[k*N + n])
// ---------------------------------------------------------------------------
__global__ void packB_k(const float* __restrict__ B, unsigned short* __restrict__ Bp,
                        int K, int N)
{
    int idx = blockIdx.x * 256 + threadIdx.x;
    if (idx >= K * N) return;
    int k = idx / N, n = idx % N;
    Bp[(((size_t)(k >> 5) * N + n) * 4 + ((k >> 3) & 3)) * 8 + (k & 7)] = f2bf(B[idx]);
}

// ---------------------------------------------------------------------------
// Wfused[l] = W[l] @ wih.T  (fp32, [6][96][288]).  Uses linearity:
//   gi = (agg @ W) @ wih.T = agg @ (W @ wih.T)  -> Stage-1 GEMM eliminated.
// ---------------------------------------------------------------------------
__global__ void wfuse_k(const float* __restrict__ W, const float* __restrict__ wih,
                        float* __restrict__ wf)
{
    int idx = blockIdx.x * 256 + threadIdx.x;
    if (idx >= LL * 96 * 288) return;
    int l = idx / (96 * 288);
    int r = idx - l * 96 * 288;
    int k = r / 288;
    int g = r - k * 288;
    const float* wr = W + (size_t)l * 9216 + (size_t)k * 96;
    const float* vr = wih + (size_t)g * 96;
    float s = 0.f;
    #pragma unroll 8
    for (int j = 0; j < 96; j++) s += wr[j] * vr[j];
    wf[idx] = s;
}

// ---------------------------------------------------------------------------
// Wgf pack: COMPACT fused gate weights, PER LAYER: [6 jb][18 ksb][64 lane][8 j]
//   ksb 0..5   -> g=0 (r), ks=ksb      (full K=192: agg-fused then h)
//   ksb 6..11  -> g=1 (z), ks=ksb-6
//   ksb 12..14 -> g=2 (i_n), ks=ksb-12 (k<96: agg side only)
//   ksb 15..17 -> g=3 (h_n), ks=ksb-12 -> 3..5 (k>=96: h side only)
// k<96 -> Wfused[l][k][n]; k>=96 -> whh[n'][k-96]
// ---------------------------------------------------------------------------
__global__ void packWgf_k(const float* __restrict__ wf, const float* __restrict__ whh,
                          unsigned short* __restrict__ Wgf)
{
    int idx = blockIdx.x * 256 + threadIdx.x;
    if (idx >= LL * 6 * 18 * 64 * 8) return;
    int l = idx / 55296;
    int r = idx - l * 55296;
    int j    = r & 7;
    int lane = (r >> 3) & 63;
    int rest = r >> 9;            // < 108
    int ksb = rest % 18;
    int jb  = rest / 18;
    int quad = lane >> 4, lc = lane & 15;
    int g, ks;
    if (ksb < 6)       { g = 0; ks = ksb; }
    else if (ksb < 12) { g = 1; ks = ksb - 6; }
    else if (ksb < 15) { g = 2; ks = ksb - 12; }
    else               { g = 3; ks = ksb - 12; }   // 3..5
    int k = ks * 32 + quad * 8 + j;
    int n = g * 96 + jb * 16 + lc;
    float v;
    if (n < 288) {
        v = (k < 96) ? wf[(size_t)l * 27648 + (size_t)k * 288 + n]
                     : whh[(size_t)n * 96 + (k - 96)];
    } else {
        v = whh[(size_t)(192 + (n - 288)) * 96 + (k - 96)];   // h_n: k>=96
    }
    Wgf[idx] = f2bf(v);
}

// combined bias pack: bs[0..95]=bih_r+bhh_r, [96..191]=bih_z+bhh_z,
// [192..287]=bih_n, [288..383]=bhh_n
__global__ void bpack_k(const float* __restrict__ bih, const float* __restrict__ bhh,
                        float* __restrict__ bs)
{
    int j = threadIdx.x;
    if (j >= 96) return;
    bs[j]        = bih[j] + bhh[j];
    bs[96 + j]   = bih[96 + j] + bhh[96 + j];
    bs[192 + j]  = bih[192 + j];
    bs[288 + j]  = bhh[192 + j];
}

__global__ void pad_k(const float* __restrict__ x, unsigned short* __restrict__ hbf)
{
    int idx = blockIdx.x * 256 + threadIdx.x;
    if (idx >= NN_ * HH) return;
    int n = idx / HH, j = idx % HH;
    float v = (j < 32) ? x[n * 32 + j] : 0.f;
    hbf[idx] = f2bf(v);
}

// --------------------------- CSR build (once per component) -----------------
__global__ void deg_k(const int* __restrict__ ei, int* __restrict__ deg)
{
    int e = blockIdx.x * 256 + threadIdx.x;
    if (e >= EE_) return;
    atomicAdd(&deg[ei[EE_ + e]], 1);
}

__global__ __launch_bounds__(SCAN_B) void scan1_k(
    const int* __restrict__ deg, int* __restrict__ rp, int* __restrict__ bsum)
{
    __shared__ int sh[SCAN_B];
    int i = blockIdx.x * SCAN_B + threadIdx.x;
    int v = (i < NN_) ? deg[i] : 0;
    sh[threadIdx.x] = v;
    __syncthreads();
    for (int off = 1; off < SCAN_B; off <<= 1) {
        int t = (threadIdx.x >= off) ? sh[threadIdx.x - off] : 0;
        __syncthreads();
        sh[threadIdx.x] += t;
        __syncthreads();
    }
    if (i < NN_) rp[i] = sh[threadIdx.x] - v;     // exclusive within block
    if (threadIdx.x == SCAN_B - 1) bsum[blockIdx.x] = sh[threadIdx.x];
}

__global__ __launch_bounds__(256) void scan2_k(int* __restrict__ bsum)
{
    __shared__ int sh[256];
    int v = (threadIdx.x < NB_SCAN) ? bsum[threadIdx.x] : 0;
    sh[threadIdx.x] = v;
    __syncthreads();
    for (int off = 1; off < 256; off <<= 1) {
        int t = (threadIdx.x >= off) ? sh[threadIdx.x - off] : 0;
        __syncthreads();
        sh[threadIdx.x] += t;
        __syncthreads();
    }
    if (threadIdx.x < NB_SCAN) bsum[threadIdx.x] = sh[threadIdx.x] - v;  // exclusive
}

__global__ void scan3_k(int* __restrict__ rp, const int* __restrict__ bsum,
                        int* __restrict__ cur)
{
    int i = blockIdx.x * 256 + threadIdx.x;
    if (i < NN_) {
        int r = rp[i] + bsum[i / SCAN_B];
        rp[i] = r;
        cur[i] = r;
    }
    if (i == 0) rp[NN_] = EE_;
}

// srcs stores BYTE offsets into the bf16 hbf rows (s * 192).
__global__ void fill_k(const int* __restrict__ ei, int* __restrict__ cur,
                       int* __restrict__ srcs)
{
    int e = blockIdx.x * 256 + threadIdx.x;
    if (e >= EE_) return;
    int s = ei[e];
    int d = ei[EE_ + e];
    int pos = atomicAdd(&cur[d], 1);
    srcs[pos] = s * 192;
}

// batch row pointers: batch[] is sorted, detect segment boundaries.
__global__ void brp_k(const int* __restrict__ bat, int* __restrict__ rpb)
{
    int i = blockIdx.x * 256 + threadIdx.x;
    if (i >= NN_) return;
    int b = bat[i];
    if (i == 0) {
        for (int q = 0; q <= b; q++) rpb[q] = 0;
    } else {
        int p = bat[i - 1];
        for (int q = p + 1; q <= b; q++) rpb[q] = i;
    }
    if (i == NN_ - 1) {
        for (int q = b + 1; q <= BB; q++) rpb[q] = NN_;
    }
}

// ---------------------------------------------------------------------------
// Phase A: aggbf[n] = sum over in-edges of hbf[src]  (bf16 out, fp32 acc).
// ---------------------------------------------------------------------------
__global__ __launch_bounds__(128) void agg_k(
    const int* __restrict__ rp, const int* __restrict__ srcs,
    const unsigned short* __restrict__ hbf,
    unsigned short* __restrict__ aggbf)
{
    int tid  = threadIdx.x;
    int wave = tid >> 6;
    int lane = tid & 63;
    int quad = lane >> 4;
    int lc   = lane & 15;
    int nT0  = blockIdx.x * 4 + wave * 2;

    const char* gbase = (const char*)hbf + quad * 16;

    #pragma unroll
    for (int t = 0; t < 2; t++) {
        int node = (nT0 + t) * 16 + lc;
        f2v ag2[12];
        #pragma unroll
        for (int i = 0; i < 12; i++) ag2[i] = (f2v){0.f, 0.f};
        int e = rp[node], e1 = rp[node + 1];
        for (; e < e1; e++) {
            const char* r = gbase + srcs[e];
            uint4 u0 = *(const uint4*)r;
            uint4 u1 = *(const uint4*)(r + 64);
            uint4 u2 = *(const uint4*)(r + 128);
            acc_row_(ag2, u0, 0); acc_row_(ag2, u1, 1); acc_row_(ag2, u2, 2);
        }
        #pragma unroll
        for (int ks = 0; ks < 3; ks++) {
            unsigned q0 = (unsigned)f2bf(ag2[ks * 4 + 0][0]) | ((unsigned)f2bf(ag2[ks * 4 + 0][1]) << 16);
            unsigned q1 = (unsigned)f2bf(ag2[ks * 4 + 1][0]) | ((unsigned)f2bf(ag2[ks * 4 + 1][1]) << 16);
            unsigned q2 = (unsigned)f2bf(ag2[ks * 4 + 2][0]) | ((unsigned)f2bf(ag2[ks * 4 + 2][1]) << 16);
            unsigned q3 = (unsigned)f2bf(ag2[ks * 4 + 3][0]) | ((unsigned)f2bf(ag2[ks * 4 + 3][1]) << 16);
            *(uint4*)(aggbf + (size_t)node * 96 + ks * 32 + quad * 8) =
                make_uint4(q0, q1, q2, q3);
        }
    }
}

// ---------------------------------------------------------------------------
// Phase B v9: FUSED-WEIGHT GRU update. Stage 1 (agg@W) eliminated via
// Wfused = W @ wih.T; gate GEMM reads [agg | h] fragments DIRECTLY.
// No as_ transpose buffer, no Wp. Structure = R7's proven shape:
// 512 thr (8 waves); grid (cdiv(NT_,16), 2); part owns jb 3p..3p+2.
// LDS = 55,296 B (3-jb fused compact weights) -> 2 blocks/CU.
// Per wave: 108 MFMA (was 144), no Stage-1 VALU pack/unpack.
// ---------------------------------------------------------------------------
__global__ __launch_bounds__(512) void gru_k(
    const unsigned short* __restrict__ aggbf,
    const unsigned short* __restrict__ Wgf,   // this layer: [6 jb][18][64][8]
    const float* __restrict__ bs,
    const unsigned short* __restrict__ hbf_prev,
    unsigned short* __restrict__ hbf_next,
    float* __restrict__ h,
    int writeH)
{
    __shared__ unsigned short lw[27648];      // 55,296 B: this part's 3 jb
    int tid  = threadIdx.x;
    int part = blockIdx.y;

    // ---- stage this part's fused weights -> LDS (coalesced 16B) ----
    {
        const uint4* src = (const uint4*)Wgf + (size_t)part * 3456;
        uint4* dst = (uint4*)lw;
        #pragma unroll
        for (int it = 0; it < 7; it++) {
            int i = it * 512 + tid;
            if (i < 3456) dst[i] = src[i];
        }
    }
    __syncthreads();

    int wave = tid >> 6;
    int lane = tid & 63;
    int quad = lane >> 4;
    int lc   = lane & 15;
    int nT0  = blockIdx.x * 16 + wave * 2;

    bool val[2];
    val[0] = (nT0 + 0) < NT_;
    val[1] = (nT0 + 1) < NT_;

    s8v z8;
    #pragma unroll
    for (int q = 0; q < 8; q++) z8[q] = 0;

    // data fragments for the gate GEMM: d[0..2] = agg (k 0..95),
    // d[3..5] = h (k 96..191) — direct coalesced loads, no Stage 1.
    s8v d[2][6];
    #pragma unroll
    for (int t = 0; t < 2; t++) {
        int node = (nT0 + t) * 16 + lc;
        #pragma unroll
        for (int ks = 0; ks < 3; ks++) {
            if (val[t]) {
                d[t][ks]     = *(const s8v*)(aggbf    + (size_t)node * 96 + ks * 32 + quad * 8);
                d[t][3 + ks] = *(const s8v*)(hbf_prev + (size_t)node * 96 + ks * 32 + quad * 8);
            } else {
                d[t][ks]     = z8;
                d[t][3 + ks] = z8;
            }
        }
    }

    // ---- gate GEMM (LDS fused weights, this part's 3 jb) + epilogue ----
    for (int jbl = 0; jbl < 3; jbl++) {
        int jb = part * 3 + jbl;
        // h_old (bf16) at this lane's OUTPUT position: 8B, L1-hot
        uint2 hu[2];
        #pragma unroll
        for (int t = 0; t < 2; t++) {
            if (val[t])
                hu[t] = *(const uint2*)(hbf_prev + (size_t)((nT0 + t) * 16 + lc) * 96 + jb * 16 + quad * 4);
            else
                hu[t] = make_uint2(0u, 0u);
        }
        f4v acc[2][4] = {};
        const unsigned short* wj = lw + (size_t)jbl * 18 * 512 + (size_t)lane * 8;
        // g = 0 (r): full K
        #pragma unroll
        for (int ks = 0; ks < 6; ks++) {
            s8v w = *(const s8v*)(wj + ks * 512);
            acc[0][0] = __builtin_amdgcn_mfma_f32_16x16x32_bf16(w, d[0][ks], acc[0][0], 0, 0, 0);
            acc[1][0] = __builtin_amdgcn_mfma_f32_16x16x32_bf16(w, d[1][ks], acc[1][0], 0, 0, 0);
        }
        // g = 1 (z): full K
        #pragma unroll
        for (int ks = 0; ks < 6; ks++) {
            s8v w = *(const s8v*)(wj + (6 + ks) * 512);
            acc[0][1] = __builtin_amdgcn_mfma_f32_16x16x32_bf16(w, d[0][ks], acc[0][1], 0, 0, 0);
            acc[1][1] = __builtin_amdgcn_mfma_f32_16x16x32_bf16(w, d[1][ks], acc[1][1], 0, 0, 0);
        }
        // g = 2 (i_n, agg side ks 0..2) and g = 3 (h_n, h side ks 3..5)
        #pragma unroll
        for (int ks = 0; ks < 6; ks++) {
            s8v w = *(const s8v*)(wj + (12 + ks) * 512);
            int g = (ks < 3) ? 2 : 3;
            acc[0][g] = __builtin_amdgcn_mfma_f32_16x16x32_bf16(w, d[0][ks], acc[0][g], 0, 0, 0);
            acc[1][g] = __builtin_amdgcn_mfma_f32_16x16x32_bf16(w, d[1][ks], acc[1][g], 0, 0, 0);
        }
        const float* bp = bs + jb * 16 + quad * 4;
        float4 br  = *(const float4*)(bp);
        float4 bz  = *(const float4*)(bp + 96);
        float4 bin = *(const float4*)(bp + 192);
        float4 bhn = *(const float4*)(bp + 288);
        float brv[4]  = {br.x, br.y, br.z, br.w};
        float bzv[4]  = {bz.x, bz.y, bz.z, bz.w};
        float binv[4] = {bin.x, bin.y, bin.z, bin.w};
        float bhnv[4] = {bhn.x, bhn.y, bhn.z, bhn.w};
        #pragma unroll
        for (int t = 0; t < 2; t++) {
            if (!val[t]) continue;
            int node = (nT0 + t) * 16 + lc;
            float hv[4];
            hv[0] = bf2f((unsigned short)(hu[t].x & 0xFFFF));
            hv[1] = bf2f((unsigned short)(hu[t].x >> 16));
            hv[2] = bf2f((unsigned short)(hu[t].y & 0xFFFF));
            hv[3] = bf2f((unsigned short)(hu[t].y >> 16));
            float out[4];
            #pragma unroll
            for (int i = 0; i < 4; i++) {
                float rg = sigmoidf_(acc[t][0][i] + brv[i]);
                float zg = sigmoidf_(acc[t][1][i] + bzv[i]);
                float nn = tanhf_(acc[t][2][i] + binv[i] + rg * (acc[t][3][i] + bhnv[i]));
                out[i] = (1.f - zg) * nn + zg * hv[i];
            }
            unsigned short q0 = f2bf(out[0]), q1 = f2bf(out[1]);
            unsigned short q2 = f2bf(out[2]), q3 = f2bf(out[3]);
            *(uint2*)(hbf_next + (size_t)node * 96 + jb * 16 + quad * 4) =
                make_uint2((unsigned)q0 | ((unsigned)q1 << 16),
                           (unsigned)q2 | ((unsigned)q3 << 16));
            if (writeH) {
                float* hp = h + (size_t)node * 96 + jb * 16 + quad * 4;
                *(float4*)hp = make_float4(out[0], out[1], out[2], out[3]);
            }
        }
    }
}

// ---------------------------------------------------------------------------
// Mean pool via sorted-batch segments: one block per graph, no atomics.
// ---------------------------------------------------------------------------
__global__ __launch_bounds__(128) void pool_csr_k(
    const float* __restrict__ h, const int* __restrict__ rpb, float* __restrict__ g)
{
    int b = blockIdx.x;
    int j = threadIdx.x;
    if (j >= 96) return;
    int n0 = rpb[b], n1 = rpb[b + 1];
    float s = 0.f;
    for (int n = n0; n < n1; n++) s += fmaxf(h[(size_t)n * 96 + j], 0.f);
    float c = (float)(n1 - n0);
    g[(size_t)b * 96 + j] = s / fmaxf(c, 1.f);
}

__global__ void feat_k(const float* __restrict__ g1, const float* __restrict__ g2,
                       const float* __restrict__ g3, float* __restrict__ feat)
{
    int idx = blockIdx.x * 256 + threadIdx.x;
    if (idx >= BB * HH) return;
    int b = idx / HH, j = idx % HH;
    float a = g1[idx], bb = g2[idx], c = g3[idx];
    float* f = feat + (size_t)b * 384;
    f[j]       = a;
    f[96 + j]  = bb;
    f[192 + j] = c;
    f[288 + j] = a * bb * c;
}

// ---------------------------------------------------------------------------
// MLP GEMM v2: C[M,N] = relu(bf16(A[M,K]) @ Bp + bias).
// grid (N/128, M/16); 4 waves share the same 16 A-rows, each owns a 32-col
// strip -> high block concurrency for latency hiding.
// ---------------------------------------------------------------------------
__global__ __launch_bounds__(256) void gemm_mlp_mfma(
    const float* __restrict__ A, const unsigned short* __restrict__ Bp,
    const float* __restrict__ bias, float* __restrict__ C,
    int K, int N, int doRelu)
{
    int wave = threadIdx.x >> 6;
    int lane = threadIdx.x & 63;
    int quad = lane >> 4;
    int lc   = lane & 15;
    int rowA = blockIdx.y * 16 + lc;
    int colb = blockIdx.x * 128 + wave * 32;

    f4v acc[2] = {};
    for (int ks = 0; ks < K / 32; ks++) {
        s8v a = load_bf8(A + (size_t)rowA * K + ks * 32 + quad * 8);
        #pragma unroll
        for (int t = 0; t < 2; t++) {
            int n = colb + t * 16 + lc;
            s8v b = *(const s8v*)(Bp + ((size_t)(ks * N + n) * 4 + quad) * 8);
            acc[t] = __builtin_amdgcn_mfma_f32_16x16x32_bf16(a, b, acc[t], 0, 0, 0);
        }
    }
    int rowD = blockIdx.y * 16 + quad * 4;
    #pragma unroll
    for (int t = 0; t < 2; t++) {
        int n = colb + t * 16 + lc;
        float bv = bias[n];
        #pragma unroll
        for (int r = 0; r < 4; r++) {
            float v = acc[t][r] + bv;
            if (doRelu) v = fmaxf(v, 0.f);
            C[(size_t)(rowD + r) * N + n] = v;
        }
    }
}

// fc3: one wave per graph, shuffle reduction.
__global__ __launch_bounds__(256) void fc3_k(const float* __restrict__ t2,
                                             const float* __restrict__ w,
                                             const float* __restrict__ bias,
                                             float* __restrict__ out)
{
    int wave = threadIdx.x >> 6;
    int lane = threadIdx.x & 63;
    int b = blockIdx.x * 4 + wave;
    const float* row = t2 + (size_t)b * 384;
    float a0 = 0.f, a1 = 0.f, a2 = 0.f;
    #pragma unroll
    for (int kk = 0; kk < 6; kk++) {
        int k = kk * 64 + lane;
        float x = row[k];
        a0 += x * w[k * 3 + 0];
        a1 += x * w[k * 3 + 1];
        a2 += x * w[k * 3 + 2];
    }
    #pragma unroll
    for (int off = 32; off > 0; off >>= 1) {
        a0 += __shfl_down(a0, off);
        a1 += __shfl_down(a1, off);
        a2 += __shfl_down(a2, off);
    }
    if (lane == 0) {
        out[b * 3 + 0] = a0 + bias[0];
        out[b * 3 + 1] = a1 + bias[1];
        out[b * 3 + 2] = a2 + bias[2];
    }
}

extern "C" void kernel_launch(void* const* d_in, const int* in_sizes, int n_in,
                              void* d_out, int out_size, void* d_ws, size_t ws_size,
                              hipStream_t stream)
{
    // Workspace (floats). Total ~50.6M f ≈ 203 MB (237 MB proven safe).
    float* ws    = (float*)d_ws;
    float* h     = ws;                               // 19,200,000 (last-layer only)
    float* hbfAF = h + (size_t)NN_ * HH;             //  9,600,000 (19.2M bf16)
    float* hbfBF = hbfAF + (size_t)NN_ * HH / 2;     //  9,600,000 (19.2M bf16)
    float* aggF  = hbfBF + (size_t)NN_ * HH / 2;     //  9,600,000 (19.2M bf16)
    float* wfF   = aggF + (size_t)NN_ * HH / 2;      //    165,888 (fp32 Wfused [6][96][288])
    float* wgfF  = wfF + 165888;                     //    165,888 (bf16 [6][55296])
    float* fc1pF = wgfF + 165888;                    //    294,912 (589,824 bf16)
    float* fc2pF = fc1pF + 294912;                   //    294,912
    float* g3    = fc2pF + 294912;                   //  1,179,648
    int*   rp    = (int*)(g3 + 3 * (size_t)BB * HH); //    200,064 ints
    int*   srcs  = rp + 200064;                      //    400,000 ints
    int*   deg   = srcs + 400000;                    //    200,000 ints
    int*   cur   = deg + 200000;                     //    200,000 ints
    int*   bsum  = cur + 200000;                     //        256 ints
    int*   rpb   = bsum + 256;                       //      4,097 ints
    float* bs    = (float*)(rpb + 4097) + 1;         //        384 f (16B-aligned region)

    unsigned short* hbfA = (unsigned short*)hbfAF;
    unsigned short* hbfB = (unsigned short*)hbfBF;
    unsigned short* agg  = (unsigned short*)aggF;
    unsigned short* Wgf  = (unsigned short*)wgfF;
    unsigned short* fc1p = (unsigned short*)fc1pF;
    unsigned short* fc2p = (unsigned short*)fc2pF;

    // MLP temps alias h (dead after pooling)
    float* feat = h;
    float* t1   = h + 2 * 1024 * 1024;
    float* t2   = h + 9 * 1024 * 1024;

    for (int c = 0; c < 3; c++) {
        const float* x   = (const float*)d_in[c * 8 + 0];
        const int*   ei  = (const int*)  d_in[c * 8 + 1];
        const int*   bat = (const int*)  d_in[c * 8 + 2];
        const float* W   = (const float*)d_in[c * 8 + 3];
        const float* wih = (const float*)d_in[c * 8 + 4];
        const float* whh = (const float*)d_in[c * 8 + 5];
        const float* bih = (const float*)d_in[c * 8 + 6];
        const float* bhh = (const float*)d_in[c * 8 + 7];

        // CSR build (once per component, reused for all 6 layers)
        hipMemsetAsync(deg, 0, NN_ * sizeof(int), stream);
        deg_k<<<cdiv(EE_, 256), 256, 0, stream>>>(ei, deg);
        scan1_k<<<NB_SCAN, SCAN_B, 0, stream>>>(deg, rp, bsum);
        scan2_k<<<1, 256, 0, stream>>>(bsum);
        scan3_k<<<cdiv(NN_, 256), 256, 0, stream>>>(rp, bsum, cur);
        fill_k<<<cdiv(EE_, 256), 256, 0, stream>>>(ei, cur, srcs);
        brp_k<<<cdiv(NN_, 256), 256, 0, stream>>>(bat, rpb);

        // fused gate weights: Wfused = W @ wih.T, then compact pack (all 6 layers)
        wfuse_k<<<cdiv(LL * 96 * 288, 256), 256, 0, stream>>>(W, wih, wfF);
        packWgf_k<<<cdiv(LL * 6 * 18 * 64 * 8, 256), 256, 0, stream>>>(wfF, whh, Wgf);
        bpack_k<<<1, 128, 0, stream>>>(bih, bhh, bs);
        pad_k<<<cdiv(NN_ * HH, 256), 256, 0, stream>>>(x, hbfA);

        unsigned short* pb[2] = {hbfA, hbfB};
        for (int l = 0; l < LL; l++) {
            agg_k<<<NN_ / 64, 128, 0, stream>>>(rp, srcs, pb[l & 1], agg);
            gru_k<<<dim3(cdiv(NT_, 16), 2), 512, 0, stream>>>(
                agg, Wgf + (size_t)l * 55296, bs, pb[l & 1], pb[(l + 1) & 1],
                h, (l == LL - 1) ? 1 : 0);
        }

        pool_csr_k<<<BB, 128, 0, stream>>>(h, rpb, g3 + (size_t)c * BB * HH);
    }

    const float* fc1_w = (const float*)d_in[24];
    const float* fc1_b = (const float*)d_in[25];
    const float* fc2_w = (const float*)d_in[26];
    const float* fc2_b = (const float*)d_in[27];
    const float* fc3_w = (const float*)d_in[28];
    const float* fc3_b = (const float*)d_in[29];

    packB_k<<<cdiv(384 * 1536, 256), 256, 0, stream>>>(fc1_w, fc1p, 384, 1536);
    packB_k<<<cdiv(1536 * 384, 256), 256, 0, stream>>>(fc2_w, fc2p, 1536, 384);

    feat_k<<<cdiv(BB * HH, 256), 256, 0, stream>>>(
        g3, g3 + (size_t)BB * HH, g3 + 2 * (size_t)BB * HH, feat);
    gemm_mlp_mfma<<<dim3(1536 / 128, BB / 16), 256, 0, stream>>>(
        feat, fc1p, fc1_b, t1, 384, 1536, 1);
    gemm_mlp_mfma<<<dim3(384 / 128, BB / 16), 256, 0, stream>>>(
        t1, fc2p, fc2_b, t2, 1536, 384, 1);
    fc3_k<<<BB / 4, 256, 0, stream>>>(t2, fc3_w, fc3_b, (float*)d_out);
}

// Round 13
// 2281.800 us; speedup vs baseline: 1.4064x; 1.0029x over previous
//
#include <hip/hip_runtime.h>
#include <math.h>

#define NN_ 200000
#define EE_ 400000
#define HH  96
#define LL  6
#define BB  4096
#define NT_ 12500     // node tiles of 16
#define SCAN_B 1024
#define NB_SCAN 196   // cdiv(200000, 1024)

typedef short s8v __attribute__((ext_vector_type(8)));
typedef float f4v __attribute__((ext_vector_type(4)));
typedef float f2v __attribute__((ext_vector_type(2)));

static inline int cdiv(int a, int b) { return (a + b - 1) / b; }

__device__ __forceinline__ float sigmoidf_(float x) { return 1.0f / (1.0f + __expf(-x)); }
__device__ __forceinline__ float tanhf_(float x) { return 1.0f - 2.0f / (__expf(2.0f * x) + 1.0f); }
__device__ __forceinline__ unsigned short f2bf(float x) {
    unsigned u = __float_as_uint(x);
    unsigned r = u + 0x7FFF + ((u >> 16) & 1);   // RNE
    return (unsigned short)(r >> 16);
}
__device__ __forceinline__ float bf2f(unsigned short u) {
    return __uint_as_float(((unsigned)u) << 16);
}
// load 8 consecutive fp32 and convert to a bf16x8 MFMA fragment (in-register)
__device__ __forceinline__ s8v load_bf8(const float* __restrict__ p) {
    float4 v0 = *(const float4*)p;
    float4 v1 = *(const float4*)(p + 4);
    s8v r;
    r[0] = (short)f2bf(v0.x); r[1] = (short)f2bf(v0.y);
    r[2] = (short)f2bf(v0.z); r[3] = (short)f2bf(v0.w);
    r[4] = (short)f2bf(v1.x); r[5] = (short)f2bf(v1.y);
    r[6] = (short)f2bf(v1.z); r[7] = (short)f2bf(v1.w);
    return r;
}

// bf16-pair accumulate: u holds 2 bf16; low elem -> a[0], high elem -> a[1]
__device__ __forceinline__ void accu_(f2v& a, unsigned u) {
    a[0] += __uint_as_float(u << 16);
    a[1] += __uint_as_float(u & 0xFFFF0000u);
}
__device__ __forceinline__ void acc_row_(f2v* ag2, const uint4& u, int ks) {
    accu_(ag2[ks * 4 + 0], u.x); accu_(ag2[ks * 4 + 1], u.y);
    accu_(ag2[ks * 4 + 2], u.z); accu_(ag2[ks * 4 + 3], u.w);
}

// ---------------------------------------------------------------------------
// MLP weight pack (B-operand fragment order, read from global):
// Bp[((k>>5)*N + n)*32 + ((k>>3)&3)*8 + (k&7)] = bf16(B[k*N + n])
// ---------------------------------------------------------------------------
__global__ void packB_k(const float* __restrict__ B, unsigned short* __restrict__ Bp,
                        int K, int N)
{
    int idx = blockIdx.x * 256 + threadIdx.x;
    if (idx >= K * N) return;
    int k = idx / N, n = idx % N;
    Bp[(((size_t)(k >> 5) * N + n) * 4 + ((k >> 3) & 3)) * 8 + (k & 7)] = f2bf(B[idx]);
}

// ---------------------------------------------------------------------------
// Wfused[l] = W[l] @ wih.T  (fp32, [6][96][288]).  Uses linearity:
//   gi = (agg @ W) @ wih.T = agg @ (W @ wih.T)  -> Stage-1 GEMM eliminated.
// ---------------------------------------------------------------------------
__global__ void wfuse_k(const float* __restrict__ W, const float* __restrict__ wih,
                        float* __restrict__ wf)
{
    int idx = blockIdx.x * 256 + threadIdx.x;
    if (idx >= LL * 96 * 288) return;
    int l = idx / (96 * 288);
    int r = idx - l * 96 * 288;
    int k = r / 288;
    int g = r - k * 288;
    const float* wr = W + (size_t)l * 9216 + (size_t)k * 96;
    const float* vr = wih + (size_t)g * 96;
    float s = 0.f;
    #pragma unroll 8
    for (int j = 0; j < 96; j++) s += wr[j] * vr[j];
    wf[idx] = s;
}

// ---------------------------------------------------------------------------
// Wgf pack: COMPACT fused gate weights, PER LAYER: [6 jb][18 ksb][64 lane][8 j]
//   ksb 0..5   -> g=0 (r), ks=ksb      (full K=192: agg-fused then h)
//   ksb 6..11  -> g=1 (z), ks=ksb-6
//   ksb 12..14 -> g=2 (i_n), ks=ksb-12 (k<96: agg side only)
//   ksb 15..17 -> g=3 (h_n), ks=ksb-12 -> 3..5 (k>=96: h side only)
// k<96 -> Wfused[l][k][n]; k>=96 -> whh[n'][k-96]
// ---------------------------------------------------------------------------
__global__ void packWgf_k(const float* __restrict__ wf, const float* __restrict__ whh,
                          unsigned short* __restrict__ Wgf)
{
    int idx = blockIdx.x * 256 + threadIdx.x;
    if (idx >= LL * 6 * 18 * 64 * 8) return;
    int l = idx / 55296;
    int r = idx - l * 55296;
    int j    = r & 7;
    int lane = (r >> 3) & 63;
    int rest = r >> 9;            // < 108
    int ksb = rest % 18;
    int jb  = rest / 18;
    int quad = lane >> 4, lc = lane & 15;
    int g, ks;
    if (ksb < 6)       { g = 0; ks = ksb; }
    else if (ksb < 12) { g = 1; ks = ksb - 6; }
    else if (ksb < 15) { g = 2; ks = ksb - 12; }
    else               { g = 3; ks = ksb - 12; }   // 3..5
    int k = ks * 32 + quad * 8 + j;
    int n = g * 96 + jb * 16 + lc;
    float v;
    if (n < 288) {
        v = (k < 96) ? wf[(size_t)l * 27648 + (size_t)k * 288 + n]
                     : whh[(size_t)n * 96 + (k - 96)];
    } else {
        v = whh[(size_t)(192 + (n - 288)) * 96 + (k - 96)];   // h_n: k>=96
    }
    Wgf[idx] = f2bf(v);
}

// combined bias pack: bs[0..95]=bih_r+bhh_r, [96..191]=bih_z+bhh_z,
// [192..287]=bih_n, [288..383]=bhh_n
__global__ void bpack_k(const float* __restrict__ bih, const float* __restrict__ bhh,
                        float* __restrict__ bs)
{
    int j = threadIdx.x;
    if (j >= 96) return;
    bs[j]        = bih[j] + bhh[j];
    bs[96 + j]   = bih[96 + j] + bhh[96 + j];
    bs[192 + j]  = bih[192 + j];
    bs[288 + j]  = bhh[192 + j];
}

__global__ void pad_k(const float* __restrict__ x, unsigned short* __restrict__ hbf)
{
    int idx = blockIdx.x * 256 + threadIdx.x;
    if (idx >= NN_ * HH) return;
    int n = idx / HH, j = idx % HH;
    float v = (j < 32) ? x[n * 32 + j] : 0.f;
    hbf[idx] = f2bf(v);
}

// --------------------------- CSR build (once per component) -----------------
__global__ void deg_k(const int* __restrict__ ei, int* __restrict__ deg)
{
    int e = blockIdx.x * 256 + threadIdx.x;
    if (e >= EE_) return;
    atomicAdd(&deg[ei[EE_ + e]], 1);
}

__global__ __launch_bounds__(SCAN_B) void scan1_k(
    const int* __restrict__ deg, int* __restrict__ rp, int* __restrict__ bsum)
{
    __shared__ int sh[SCAN_B];
    int i = blockIdx.x * SCAN_B + threadIdx.x;
    int v = (i < NN_) ? deg[i] : 0;
    sh[threadIdx.x] = v;
    __syncthreads();
    for (int off = 1; off < SCAN_B; off <<= 1) {
        int t = (threadIdx.x >= off) ? sh[threadIdx.x - off] : 0;
        __syncthreads();
        sh[threadIdx.x] += t;
        __syncthreads();
    }
    if (i < NN_) rp[i] = sh[threadIdx.x] - v;     // exclusive within block
    if (threadIdx.x == SCAN_B - 1) bsum[blockIdx.x] = sh[threadIdx.x];
}

__global__ __launch_bounds__(256) void scan2_k(int* __restrict__ bsum)
{
    __shared__ int sh[256];
    int v = (threadIdx.x < NB_SCAN) ? bsum[threadIdx.x] : 0;
    sh[threadIdx.x] = v;
    __syncthreads();
    for (int off = 1; off < 256; off <<= 1) {
        int t = (threadIdx.x >= off) ? sh[threadIdx.x - off] : 0;
        __syncthreads();
        sh[threadIdx.x] += t;
        __syncthreads();
    }
    if (threadIdx.x < NB_SCAN) bsum[threadIdx.x] = sh[threadIdx.x] - v;  // exclusive
}

__global__ void scan3_k(int* __restrict__ rp, const int* __restrict__ bsum,
                        int* __restrict__ cur)
{
    int i = blockIdx.x * 256 + threadIdx.x;
    if (i < NN_) {
        int r = rp[i] + bsum[i / SCAN_B];
        rp[i] = r;
        cur[i] = r;
    }
    if (i == 0) rp[NN_] = EE_;
}

// srcs stores BYTE offsets into the bf16 hbf rows (s * 192).
__global__ void fill_k(const int* __restrict__ ei, int* __restrict__ cur,
                       int* __restrict__ srcs)
{
    int e = blockIdx.x * 256 + threadIdx.x;
    if (e >= EE_) return;
    int s = ei[e];
    int d = ei[EE_ + e];
    int pos = atomicAdd(&cur[d], 1);
    srcs[pos] = s * 192;
}

// batch row pointers: batch[] is sorted, detect segment boundaries.
__global__ void brp_k(const int* __restrict__ bat, int* __restrict__ rpb)
{
    int i = blockIdx.x * 256 + threadIdx.x;
    if (i >= NN_) return;
    int b = bat[i];
    if (i == 0) {
        for (int q = 0; q <= b; q++) rpb[q] = 0;
    } else {
        int p = bat[i - 1];
        for (int q = p + 1; q <= b; q++) rpb[q] = i;
    }
    if (i == NN_ - 1) {
        for (int q = b + 1; q <= BB; q++) rpb[q] = NN_;
    }
}

// ---------------------------------------------------------------------------
// Fully fused layer v10: gather + fused-weight gate GEMM + GRU epilogue in
// ONE dispatch per layer. The CSR gather's per-lane layout (node lc, feats
// ks*32+quad*8..+8) IS the MFMA fragment layout, so gather sums convert
// directly into d[t][ks] — no agg buffer, no round-trip.
// 512 thr (8 waves); grid (cdiv(NT_,16), 2); part owns jb 3p..3p+2.
// LDS 55,296 B (3-jb fused weights) -> 2 blocks/CU. Gather duplicated per
// part (L3-served). Weight stage issued BEFORE gather to overlap.
// ---------------------------------------------------------------------------
__global__ __launch_bounds__(512) void layer_k(
    const int* __restrict__ rp, const int* __restrict__ srcs,
    const unsigned short* __restrict__ Wgf,   // this layer: [6 jb][18][64][8]
    const float* __restrict__ bs,
    const unsigned short* __restrict__ hbf_prev,
    unsigned short* __restrict__ hbf_next,
    float* __restrict__ h,
    int writeH)
{
    __shared__ unsigned short lw[27648];      // 55,296 B: this part's 3 jb
    int tid  = threadIdx.x;
    int part = blockIdx.y;

    // ---- stage this part's fused weights -> LDS (issues early, overlaps
    //      with the gather below; barrier is after the gather) ----
    {
        const uint4* src = (const uint4*)Wgf + (size_t)part * 3456;
        uint4* dst = (uint4*)lw;
        #pragma unroll
        for (int it = 0; it < 7; it++) {
            int i = it * 512 + tid;
            if (i < 3456) dst[i] = src[i];
        }
    }

    int wave = tid >> 6;
    int lane = tid & 63;
    int quad = lane >> 4;
    int lc   = lane & 15;
    int nT0  = blockIdx.x * 16 + wave * 2;

    bool val[2];
    val[0] = (nT0 + 0) < NT_;
    val[1] = (nT0 + 1) < NT_;

    s8v z8;
    #pragma unroll
    for (int q = 0; q < 8; q++) z8[q] = 0;

    // hoist CSR ranges
    int n0 = nT0 * 16 + lc;
    int e0t[2] = {0, 0}, e1t[2] = {0, 0};
    if (val[0]) { e0t[0] = rp[n0];      e1t[0] = rp[n0 + 1]; }
    if (val[1]) { e0t[1] = rp[n0 + 16]; e1t[1] = rp[n0 + 17]; }

    const char* gbase = (const char*)hbf_prev + quad * 16;

    // ---- Stage 0: gather -> d[t][0..2] (agg side of K); own-row h -> d[t][3..5]
    s8v d[2][6];
    #pragma unroll
    for (int t = 0; t < 2; t++) {
        f2v ag2[12];
        #pragma unroll
        for (int i = 0; i < 12; i++) ag2[i] = (f2v){0.f, 0.f};
        for (int e = e0t[t]; e < e1t[t]; e++) {
            const char* r = gbase + srcs[e];
            uint4 u0 = *(const uint4*)r;
            uint4 u1 = *(const uint4*)(r + 64);
            uint4 u2 = *(const uint4*)(r + 128);
            acc_row_(ag2, u0, 0); acc_row_(ag2, u1, 1); acc_row_(ag2, u2, 2);
        }
        #pragma unroll
        for (int ks = 0; ks < 3; ks++) {
            s8v v;
            #pragma unroll
            for (int w = 0; w < 4; w++) {
                v[2 * w]     = (short)f2bf(ag2[ks * 4 + w][0]);
                v[2 * w + 1] = (short)f2bf(ag2[ks * 4 + w][1]);
            }
            d[t][ks] = v;
        }
        int node = (nT0 + t) * 16 + lc;
        #pragma unroll
        for (int ks = 0; ks < 3; ks++) {
            d[t][3 + ks] = val[t]
                ? *(const s8v*)(hbf_prev + (size_t)node * 96 + ks * 32 + quad * 8)
                : z8;
        }
    }

    __syncthreads();   // weight stage complete

    // ---- gate GEMM (LDS fused weights, this part's 3 jb) + epilogue ----
    for (int jbl = 0; jbl < 3; jbl++) {
        int jb = part * 3 + jbl;
        // h_old (bf16) at this lane's OUTPUT position: 8B, L1-hot
        uint2 hu[2];
        #pragma unroll
        for (int t = 0; t < 2; t++) {
            if (val[t])
                hu[t] = *(const uint2*)(hbf_prev + (size_t)((nT0 + t) * 16 + lc) * 96 + jb * 16 + quad * 4);
            else
                hu[t] = make_uint2(0u, 0u);
        }
        f4v acc[2][4] = {};
        const unsigned short* wj = lw + (size_t)jbl * 18 * 512 + (size_t)lane * 8;
        // g = 0 (r): full K
        #pragma unroll
        for (int ks = 0; ks < 6; ks++) {
            s8v w = *(const s8v*)(wj + ks * 512);
            acc[0][0] = __builtin_amdgcn_mfma_f32_16x16x32_bf16(w, d[0][ks], acc[0][0], 0, 0, 0);
            acc[1][0] = __builtin_amdgcn_mfma_f32_16x16x32_bf16(w, d[1][ks], acc[1][0], 0, 0, 0);
        }
        // g = 1 (z): full K
        #pragma unroll
        for (int ks = 0; ks < 6; ks++) {
            s8v w = *(const s8v*)(wj + (6 + ks) * 512);
            acc[0][1] = __builtin_amdgcn_mfma_f32_16x16x32_bf16(w, d[0][ks], acc[0][1], 0, 0, 0);
            acc[1][1] = __builtin_amdgcn_mfma_f32_16x16x32_bf16(w, d[1][ks], acc[1][1], 0, 0, 0);
        }
        // g = 2 (i_n, agg side ks 0..2) and g = 3 (h_n, h side ks 3..5)
        #pragma unroll
        for (int ks = 0; ks < 6; ks++) {
            s8v w = *(const s8v*)(wj + (12 + ks) * 512);
            int g = (ks < 3) ? 2 : 3;
            acc[0][g] = __builtin_amdgcn_mfma_f32_16x16x32_bf16(w, d[0][ks], acc[0][g], 0, 0, 0);
            acc[1][g] = __builtin_amdgcn_mfma_f32_16x16x32_bf16(w, d[1][ks], acc[1][g], 0, 0, 0);
        }
        const float* bp = bs + jb * 16 + quad * 4;
        float4 br  = *(const float4*)(bp);
        float4 bz  = *(const float4*)(bp + 96);
        float4 bin = *(const float4*)(bp + 192);
        float4 bhn = *(const float4*)(bp + 288);
        float brv[4]  = {br.x, br.y, br.z, br.w};
        float bzv[4]  = {bz.x, bz.y, bz.z, bz.w};
        float binv[4] = {bin.x, bin.y, bin.z, bin.w};
        float bhnv[4] = {bhn.x, bhn.y, bhn.z, bhn.w};
        #pragma unroll
        for (int t = 0; t < 2; t++) {
            if (!val[t]) continue;
            int node = (nT0 + t) * 16 + lc;
            float hv[4];
            hv[0] = bf2f((unsigned short)(hu[t].x & 0xFFFF));
            hv[1] = bf2f((unsigned short)(hu[t].x >> 16));
            hv[2] = bf2f((unsigned short)(hu[t].y & 0xFFFF));
            hv[3] = bf2f((unsigned short)(hu[t].y >> 16));
            float out[4];
            #pragma unroll
            for (int i = 0; i < 4; i++) {
                float rg = sigmoidf_(acc[t][0][i] + brv[i]);
                float zg = sigmoidf_(acc[t][1][i] + bzv[i]);
                float nn = tanhf_(acc[t][2][i] + binv[i] + rg * (acc[t][3][i] + bhnv[i]));
                out[i] = (1.f - zg) * nn + zg * hv[i];
            }
            unsigned short q0 = f2bf(out[0]), q1 = f2bf(out[1]);
            unsigned short q2 = f2bf(out[2]), q3 = f2bf(out[3]);
            *(uint2*)(hbf_next + (size_t)node * 96 + jb * 16 + quad * 4) =
                make_uint2((unsigned)q0 | ((unsigned)q1 << 16),
                           (unsigned)q2 | ((unsigned)q3 << 16));
            if (writeH) {
                float* hp = h + (size_t)node * 96 + jb * 16 + quad * 4;
                *(float4*)hp = make_float4(out[0], out[1], out[2], out[3]);
            }
        }
    }
}

// ---------------------------------------------------------------------------
// Mean pool via sorted-batch segments: one block per graph, no atomics.
// ---------------------------------------------------------------------------
__global__ __launch_bounds__(128) void pool_csr_k(
    const float* __restrict__ h, const int* __restrict__ rpb, float* __restrict__ g)
{
    int b = blockIdx.x;
    int j = threadIdx.x;
    if (j >= 96) return;
    int n0 = rpb[b], n1 = rpb[b + 1];
    float s = 0.f;
    for (int n = n0; n < n1; n++) s += fmaxf(h[(size_t)n * 96 + j], 0.f);
    float c = (float)(n1 - n0);
    g[(size_t)b * 96 + j] = s / fmaxf(c, 1.f);
}

__global__ void feat_k(const float* __restrict__ g1, const float* __restrict__ g2,
                       const float* __restrict__ g3, float* __restrict__ feat)
{
    int idx = blockIdx.x * 256 + threadIdx.x;
    if (idx >= BB * HH) return;
    int b = idx / HH, j = idx % HH;
    float a = g1[idx], bb = g2[idx], c = g3[idx];
    float* f = feat + (size_t)b * 384;
    f[j]       = a;
    f[96 + j]  = bb;
    f[192 + j] = c;
    f[288 + j] = a * bb * c;
}

// ---------------------------------------------------------------------------
// MLP GEMM v2: C[M,N] = relu(bf16(A[M,K]) @ Bp + bias).
// grid (N/128, M/16); 4 waves share the same 16 A-rows, each owns a 32-col
// strip -> high block concurrency for latency hiding.
// ---------------------------------------------------------------------------
__global__ __launch_bounds__(256) void gemm_mlp_mfma(
    const float* __restrict__ A, const unsigned short* __restrict__ Bp,
    const float* __restrict__ bias, float* __restrict__ C,
    int K, int N, int doRelu)
{
    int wave = threadIdx.x >> 6;
    int lane = threadIdx.x & 63;
    int quad = lane >> 4;
    int lc   = lane & 15;
    int rowA = blockIdx.y * 16 + lc;
    int colb = blockIdx.x * 128 + wave * 32;

    f4v acc[2] = {};
    for (int ks = 0; ks < K / 32; ks++) {
        s8v a = load_bf8(A + (size_t)rowA * K + ks * 32 + quad * 8);
        #pragma unroll
        for (int t = 0; t < 2; t++) {
            int n = colb + t * 16 + lc;
            s8v b = *(const s8v*)(Bp + ((size_t)(ks * N + n) * 4 + quad) * 8);
            acc[t] = __builtin_amdgcn_mfma_f32_16x16x32_bf16(a, b, acc[t], 0, 0, 0);
        }
    }
    int rowD = blockIdx.y * 16 + quad * 4;
    #pragma unroll
    for (int t = 0; t < 2; t++) {
        int n = colb + t * 16 + lc;
        float bv = bias[n];
        #pragma unroll
        for (int r = 0; r < 4; r++) {
            float v = acc[t][r] + bv;
            if (doRelu) v = fmaxf(v, 0.f);
            C[(size_t)(rowD + r) * N + n] = v;
        }
    }
}

// fc3: one wave per graph, shuffle reduction.
__global__ __launch_bounds__(256) void fc3_k(const float* __restrict__ t2,
                                             const float* __restrict__ w,
                                             const float* __restrict__ bias,
                                             float* __restrict__ out)
{
    int wave = threadIdx.x >> 6;
    int lane = threadIdx.x & 63;
    int b = blockIdx.x * 4 + wave;
    const float* row = t2 + (size_t)b * 384;
    float a0 = 0.f, a1 = 0.f, a2 = 0.f;
    #pragma unroll
    for (int kk = 0; kk < 6; kk++) {
        int k = kk * 64 + lane;
        float x = row[k];
        a0 += x * w[k * 3 + 0];
        a1 += x * w[k * 3 + 1];
        a2 += x * w[k * 3 + 2];
    }
    #pragma unroll
    for (int off = 32; off > 0; off >>= 1) {
        a0 += __shfl_down(a0, off);
        a1 += __shfl_down(a1, off);
        a2 += __shfl_down(a2, off);
    }
    if (lane == 0) {
        out[b * 3 + 0] = a0 + bias[0];
        out[b * 3 + 1] = a1 + bias[1];
        out[b * 3 + 2] = a2 + bias[2];
    }
}

extern "C" void kernel_launch(void* const* d_in, const int* in_sizes, int n_in,
                              void* d_out, int out_size, void* d_ws, size_t ws_size,
                              hipStream_t stream)
{
    // Workspace (floats). Total ~41.5M f ≈ 166 MB (237 MB proven safe).
    float* ws    = (float*)d_ws;
    float* h     = ws;                               // 19,200,000 (last-layer only)
    float* hbfAF = h + (size_t)NN_ * HH;             //  9,600,000 (19.2M bf16)
    float* hbfBF = hbfAF + (size_t)NN_ * HH / 2;     //  9,600,000 (19.2M bf16)
    float* wfF   = hbfBF + (size_t)NN_ * HH / 2;     //    165,888 (fp32 Wfused [6][96][288])
    float* wgfF  = wfF + 165888;                     //    165,888 (bf16 [6][55296])
    float* fc1pF = wgfF + 165888;                    //    294,912 (589,824 bf16)
    float* fc2pF = fc1pF + 294912;                   //    294,912
    float* g3    = fc2pF + 294912;                   //  1,179,648
    int*   rp    = (int*)(g3 + 3 * (size_t)BB * HH); //    200,064 ints
    int*   srcs  = rp + 200064;                      //    400,000 ints
    int*   deg   = srcs + 400000;                    //    200,000 ints
    int*   cur   = deg + 200000;                     //    200,000 ints
    int*   bsum  = cur + 200000;                     //        256 ints
    int*   rpb   = bsum + 256;                       //      4,097 ints
    float* bs    = (float*)(rpb + 4097) + 1;         //        384 f (16B-aligned region)

    unsigned short* hbfA = (unsigned short*)hbfAF;
    unsigned short* hbfB = (unsigned short*)hbfBF;
    unsigned short* Wgf  = (unsigned short*)wgfF;
    unsigned short* fc1p = (unsigned short*)fc1pF;
    unsigned short* fc2p = (unsigned short*)fc2pF;

    // MLP temps alias h (dead after pooling)
    float* feat = h;
    float* t1   = h + 2 * 1024 * 1024;
    float* t2   = h + 9 * 1024 * 1024;

    for (int c = 0; c < 3; c++) {
        const float* x   = (const float*)d_in[c * 8 + 0];
        const int*   ei  = (const int*)  d_in[c * 8 + 1];
        const int*   bat = (const int*)  d_in[c * 8 + 2];
        const float* W   = (const float*)d_in[c * 8 + 3];
        const float* wih = (const float*)d_in[c * 8 + 4];
        const float* whh = (const float*)d_in[c * 8 + 5];
        const float* bih = (const float*)d_in[c * 8 + 6];
        const float* bhh = (const float*)d_in[c * 8 + 7];

        // CSR build (once per component, reused for all 6 layers)
        hipMemsetAsync(deg, 0, NN_ * sizeof(int), stream);
        deg_k<<<cdiv(EE_, 256), 256, 0, stream>>>(ei, deg);
        scan1_k<<<NB_SCAN, SCAN_B, 0, stream>>>(deg, rp, bsum);
        scan2_k<<<1, 256, 0, stream>>>(bsum);
        scan3_k<<<cdiv(NN_, 256), 256, 0, stream>>>(rp, bsum, cur);
        fill_k<<<cdiv(EE_, 256), 256, 0, stream>>>(ei, cur, srcs);
        brp_k<<<cdiv(NN_, 256), 256, 0, stream>>>(bat, rpb);

        // fused gate weights: Wfused = W @ wih.T, then compact pack (all 6 layers)
        wfuse_k<<<cdiv(LL * 96 * 288, 256), 256, 0, stream>>>(W, wih, wfF);
        packWgf_k<<<cdiv(LL * 6 * 18 * 64 * 8, 256), 256, 0, stream>>>(wfF, whh, Wgf);
        bpack_k<<<1, 128, 0, stream>>>(bih, bhh, bs);
        pad_k<<<cdiv(NN_ * HH, 256), 256, 0, stream>>>(x, hbfA);

        unsigned short* pb[2] = {hbfA, hbfB};
        for (int l = 0; l < LL; l++) {
            layer_k<<<dim3(cdiv(NT_, 16), 2), 512, 0, stream>>>(
                rp, srcs, Wgf + (size_t)l * 55296, bs, pb[l & 1], pb[(l + 1) & 1],
                h, (l == LL - 1) ? 1 : 0);
        }

        pool_csr_k<<<BB, 128, 0, stream>>>(h, rpb, g3 + (size_t)c * BB * HH);
    }

    const float* fc1_w = (const float*)d_in[24];
    const float* fc1_b = (const float*)d_in[25];
    const float* fc2_w = (const float*)d_in[26];
    const float* fc2_b = (const float*)d_in[27];
    const float* fc3_w = (const float*)d_in[28];
    const float* fc3_b = (const float*)d_in[29];

    packB_k<<<cdiv(384 * 1536, 256), 256, 0, stream>>>(fc1_w, fc1p, 384, 1536);
    packB_k<<<cdiv(1536 * 384, 256), 256, 0, stream>>>(fc2_w, fc2p, 1536, 384);

    feat_k<<<cdiv(BB * HH, 256), 256, 0, stream>>>(
        g3, g3 + (size_t)BB * HH, g3 + 2 * (size_t)BB * HH, feat);
    gemm_mlp_mfma<<<dim3(1536 / 128, BB / 16), 256, 0, stream>>>(
        feat, fc1p, fc1_b, t1, 384, 1536, 1);
    gemm_mlp_mfma<<<dim3(384 / 128, BB / 16), 256, 0, stream>>>(
        t1, fc2p, fc2_b, t2, 1536, 384, 1);
    fc3_k<<<BB / 4, 256, 0, stream>>>(t2, fc3_w, fc3_b, (float*)d_out);
}